// Round 1
// 696.820 us; speedup vs baseline: 1.3054x; 1.3054x over previous
//
#include <hip/hip_runtime.h>
#include <hip/hip_bf16.h>

#define NN 100000
#define NE 1600000
#define INDIM 128
#define HID 64
#define SCANB 98   // ceil(NN / 1024)

typedef __hip_bfloat16 bf16;
typedef unsigned short ushort;
typedef unsigned int uint;
typedef __attribute__((ext_vector_type(8))) short short8;
typedef __attribute__((ext_vector_type(4))) float floatx4;

__device__ __forceinline__ float b2f(bf16 v) { return __bfloat162float(v); }
__device__ __forceinline__ float b2f_raw(ushort u) { return __uint_as_float(((uint)u) << 16); }
__device__ __forceinline__ ushort f2bu(float v) {
    bf16 t = __float2bfloat16(v);
    return *reinterpret_cast<ushort*>(&t);
}
// flag-aware input load: f32==1 -> fp32 tensor, else bf16 tensor
__device__ __forceinline__ float ldin(const void* p, int i, int f32) {
    return f32 ? ((const float*)p)[i] : b2f(((const bf16*)p)[i]);
}
__device__ __forceinline__ float sigmoidf(float x) { return 1.f / (1.f + __expf(-x)); }
__device__ __forceinline__ float tanh_fast(float x) {
    float e = __expf(2.f * x);
    return 1.f - 2.f / (e + 1.f);
}
__device__ __forceinline__ uint4 packf8(const float* f) {
    uint4 u;
    u.x = f2bu(f[0]) | ((uint)f2bu(f[1]) << 16);
    u.y = f2bu(f[2]) | ((uint)f2bu(f[3]) << 16);
    u.z = f2bu(f[4]) | ((uint)f2bu(f[5]) << 16);
    u.w = f2bu(f[6]) | ((uint)f2bu(f[7]) << 16);
    return u;
}
// 8 consecutive elements of a (bf16|fp32) tensor as packed bf16
__device__ __forceinline__ uint4 ld8_bf16(const void* p, int off, int f32) {
    if (!f32) return *(const uint4*)((const ushort*)p + off);
    const float* q = (const float*)p + off;
    float4 a = *(const float4*)q, b = *(const float4*)(q + 4);
    float f[8] = {a.x, a.y, a.z, a.w, b.x, b.y, b.z, b.w};
    return packf8(f);
}

// ---------------- dtype sniffer ----------------------------------------
__global__ void k_sniff(const void* __restrict__ x, int* __restrict__ flag) {
    __shared__ int cnt;
    if (threadIdx.x == 0) cnt = 0;
    __syncthreads();
    const bf16* p = (const bf16*)x;
    int bad = 0;
    for (int i = threadIdx.x; i < 8192; i += 256) {
        float v = b2f(p[i]);
        if (!(fabsf(v) < 1e6f)) bad++;
    }
    atomicAdd(&cnt, bad);
    __syncthreads();
    if (threadIdx.x == 0) flag[0] = (cnt > 32) ? 1 : 0;
}

// ---------------- degree (over src) + in-degree histogram (over dst) ---
__global__ void k_deghist(const int* __restrict__ ei, const void* __restrict__ ew,
                          float* __restrict__ deg, int* __restrict__ cnt,
                          const int* __restrict__ flagp) {
    const int f32 = flagp[0];
    int e = blockIdx.x * 256 + threadIdx.x;   // grid exactly NE
    int src = ei[e], dst = ei[NE + e];
    if (src != dst) {
        atomicAdd(deg + src, ldin(ew, e, f32));
        atomicAdd(cnt + dst, 1);
    }
}

__global__ void k_dinv(float* __restrict__ buf) {
    int n = blockIdx.x * 256 + threadIdx.x;
    if (n < NN) { float d = buf[n]; buf[n] = d > 0.f ? rsqrtf(d) : 0.f; }
}

// ---------------- device-wide scan: cnt -> rowptr, wptr ----------------
// pass 1: per-block (1024-element) sums
__global__ __launch_bounds__(256)
void k_scan1(const int* __restrict__ cnt, int* __restrict__ bsum) {
    const int t = threadIdx.x, b = blockIdx.x;
    const int base = b * 1024 + t * 4;
    int s = 0;
    if (base + 3 < NN) {
        int4 v = *(const int4*)(cnt + base);
        s = v.x + v.y + v.z + v.w;
    } else {
#pragma unroll
        for (int i = 0; i < 4; i++) if (base + i < NN) s += cnt[base + i];
    }
#pragma unroll
    for (int off = 32; off; off >>= 1) s += __shfl_xor(s, off);
    __shared__ int wsum[4];
    if ((t & 63) == 0) wsum[t >> 6] = s;
    __syncthreads();
    if (t == 0) bsum[b] = wsum[0] + wsum[1] + wsum[2] + wsum[3];
}

// pass 2: scan the 98 block sums (single tiny block)
__global__ __launch_bounds__(128)
void k_scan2(const int* __restrict__ bsum, int* __restrict__ boff,
             int* __restrict__ rowptr) {
    __shared__ int sh[128];
    const int t = threadIdx.x;
    int v = (t < SCANB) ? bsum[t] : 0;
    sh[t] = v;
    __syncthreads();
    for (int off = 1; off < 128; off <<= 1) {
        int u = (t >= off) ? sh[t - off] : 0;
        __syncthreads();
        sh[t] += u;
        __syncthreads();
    }
    if (t < SCANB) boff[t] = sh[t] - v;        // exclusive block offset
    if (t == SCANB - 1) rowptr[NN] = sh[t];    // grand total
}

// pass 3: local prefix + block offset -> rowptr, wptr
__global__ __launch_bounds__(256)
void k_scan3(const int* __restrict__ cnt, const int* __restrict__ boff,
             int* __restrict__ rowptr, int* __restrict__ wptr) {
    const int t = threadIdx.x, b = blockIdx.x;
    const int lane = t & 63, w = t >> 6;
    const int base = b * 1024 + t * 4;
    int v0 = 0, v1 = 0, v2 = 0, v3 = 0;
    if (base + 3 < NN) {
        int4 v = *(const int4*)(cnt + base);
        v0 = v.x; v1 = v.y; v2 = v.z; v3 = v.w;
    } else {
        if (base + 0 < NN) v0 = cnt[base + 0];
        if (base + 1 < NN) v1 = cnt[base + 1];
        if (base + 2 < NN) v2 = cnt[base + 2];
    }
    int tsum = v0 + v1 + v2 + v3;
    int inc = tsum;                            // wave inclusive scan
#pragma unroll
    for (int off = 1; off < 64; off <<= 1) {
        int u = __shfl_up(inc, off);
        if (lane >= off) inc += u;
    }
    __shared__ int wtot[4];
    if (lane == 63) wtot[w] = inc;
    __syncthreads();
    int woff = 0;
#pragma unroll
    for (int i = 0; i < 4; i++) if (i < w) woff += wtot[i];
    const int off0 = boff[b] + woff + (inc - tsum);
    int4 r;
    r.x = off0;
    r.y = off0 + v0;
    r.z = off0 + v0 + v1;
    r.w = off0 + v0 + v1 + v2;
    if (base + 3 < NN) {
        *(int4*)(rowptr + base) = r;
        *(int4*)(wptr + base) = r;
    } else {
        if (base + 0 < NN) { rowptr[base + 0] = r.x; wptr[base + 0] = r.x; }
        if (base + 1 < NN) { rowptr[base + 1] = r.y; wptr[base + 1] = r.y; }
        if (base + 2 < NN) { rowptr[base + 2] = r.z; wptr[base + 2] = r.z; }
    }
}

// ---------------- fill CSR: packed (src, lw) per dst slot --------------
__global__ void k_fill(const int* __restrict__ ei, const void* __restrict__ ew,
                       const float* __restrict__ dinv, int* __restrict__ wptr,
                       int2* __restrict__ csr, const int* __restrict__ flagp) {
    const int f32 = flagp[0];
    int e = blockIdx.x * 256 + threadIdx.x;   // grid exactly NE
    int src = ei[e], dst = ei[NE + e];
    if (src == dst) return;
    float lw = -dinv[src] * ldin(ew, e, f32) * dinv[dst];
    int pos = atomicAdd(wptr + dst, 1);
    int2 p; p.x = src; p.y = __float_as_int(lw);
    csr[pos] = p;
}

// ---------------- gather SpMM: one wave per dst, register accumulate ---
template<bool BF16IN>
__global__ __launch_bounds__(256)
void k_gath(const int* __restrict__ rowptr, const int2* __restrict__ csr,
            const void* __restrict__ zin, float* __restrict__ outv,
            const int* __restrict__ flagp) {
    const int f32 = flagp[0];
    int w = (blockIdx.x * 256 + threadIdx.x) >> 6;   // dst node
    int lane = threadIdx.x & 63;
    if (w >= NN) return;
    int b = rowptr[w], e = rowptr[w + 1];
    float acc = 0.f;
    int i = b;
    for (; i + 1 < e; i += 2) {
        int2 p0 = csr[i], p1 = csr[i + 1];
        float z0 = BF16IN ? ldin(zin, p0.x * 64 + lane, f32)
                          : ((const float*)zin)[p0.x * 64 + lane];
        float z1 = BF16IN ? ldin(zin, p1.x * 64 + lane, f32)
                          : ((const float*)zin)[p1.x * 64 + lane];
        acc = fmaf(__int_as_float(p0.y), z0, acc);
        acc = fmaf(__int_as_float(p1.y), z1, acc);
    }
    if (i < e) {
        int2 p0 = csr[i];
        float z0 = BF16IN ? ldin(zin, p0.x * 64 + lane, f32)
                          : ((const float*)zin)[p0.x * 64 + lane];
        acc = fmaf(__int_as_float(p0.y), z0, acc);
    }
    outv[w * 64 + lane] = acc;
}

// ---------------- pre-swizzle weights into MFMA fragment order ---------
// Wf: [kc 0..9][t 0..15][lane 0..63][j 0..7] bf16, element =
//     W[r = kc*32 + (lane>>4)*8 + j][o = 16t + (lane&15)] with column perm
//     o = 16t+(l&15): gate g = t&3, cc = (t>>2)*16 + (lane&15)
// WlF: [kc2 0..1][t 0..3][lane][j], Wl[k = kc2*32+(l>>4)*8+j][n = 16t+(l&15)]
// biasP[o]: permuted bias
__global__ void k_wcat(const void* __restrict__ Wx, const void* __restrict__ theta,
                       const void* __restrict__ bg, const void* __restrict__ convb,
                       const void* __restrict__ Wl,
                       ushort* __restrict__ Wf, float* __restrict__ biasP,
                       ushort* __restrict__ WlF, const int* __restrict__ flagp) {
    const int f32 = flagp[0];
    int gid = blockIdx.x * 256 + threadIdx.x;   // 336 blocks * 256 = 86016
    if (gid < 81920) {
        int j = gid & 7, l = (gid >> 3) & 63, tile = gid >> 9;
        int kc = tile >> 4, t = tile & 15;
        int r = kc * 32 + ((l >> 4) * 8) + j;
        int g = t & 3;
        int cc = (t >> 2) * 16 + (l & 15);
        float v;
        if (r < 128) {
            v = ldin(Wx, (g * 128 + r) * 64 + cc, f32);
        } else {
            int k3 = (r - 128) >> 6, rr = (r - 128) & 63;
            v = ldin(theta, ((g * 3 + k3) * 64 + rr) * 64 + cc, f32);
        }
        Wf[gid] = f2bu(v);
        if (gid < 256) {
            int o = gid;
            int gg = (o >> 4) & 3;
            int cc2 = (o >> 6) * 16 + (o & 15);
            biasP[o] = ldin(bg, gg * 64 + cc2, f32) + ldin(convb, gg * 64 + cc2, f32);
        }
    } else {
        int gid2 = gid - 81920;                  // [0, 4096)
        int j = gid2 & 7, l = (gid2 >> 3) & 63, tile2 = gid2 >> 9;
        int kc2 = tile2 >> 2, t = tile2 & 3;
        int k = kc2 * 32 + ((l >> 4) * 8) + j;
        int n = t * 16 + (l & 15);
        WlF[gid2] = f2bu(ldin(Wl, k * 64 + n, f32));
    }
}

// ---------------- MFMA gate GEMM [64 nodes x 256 cols] + LSTM + out ----
// F rows: 0-127 x | 128-191 h | 192-255 Tx1 | 256-319 (2*agg2 - h)
// Aliasing: Tx1 lives in `out` fp32 region, agg2 in `c0` fp32 region —
// same-dtype same-row mapping, blocks only touch their own 64-node slab,
// all reads precede all writes within the block. Safe.
__global__ __launch_bounds__(256)
void k_gates(const void* __restrict__ x, const void* __restrict__ h,
             const void* __restrict__ cin,
             const float* __restrict__ Tx1, const float* __restrict__ agg2,
             const ushort* __restrict__ Wf, const float* __restrict__ biasP,
             const ushort* __restrict__ WlF, const void* __restrict__ bl,
             float* __restrict__ outF, float* __restrict__ h0o,
             float* __restrict__ c0o, const int* __restrict__ flagp) {
    const int f32 = flagp[0];
    __shared__ ushort As[4 * 64 * 8];    // 4 KB, A fragments for one 64x32 chunk
    __shared__ ushort Hs[64 * 72];       // 9.2 KB, relu(h0) bf16, padded stride 72
    const int tid = threadIdx.x;
    const int lane = tid & 63;
    const int w = tid >> 6;              // wave 0..3
    const int base = blockIdx.x * 64;
    // staging role: thread -> (node sm, k-quad skq)
    const int sm = tid & 63;
    const int skq = tid >> 6;
    const int snode = base + sm;
    const bool svalid = snode < NN;
    uint4* sdst = (uint4*)&As[(((sm >> 4) * 64) + ((sm & 15) + 16 * skq)) * 8];

    floatx4 acc[4][4];                   // [m-tile][gate]
    {
        float bv0 = biasP[w * 64 + 0 * 16 + (lane & 15)];
        float bv1 = biasP[w * 64 + 1 * 16 + (lane & 15)];
        float bv2 = biasP[w * 64 + 2 * 16 + (lane & 15)];
        float bv3 = biasP[w * 64 + 3 * 16 + (lane & 15)];
#pragma unroll
        for (int mt = 0; mt < 4; mt++) {
            acc[mt][0] = (floatx4){bv0, bv0, bv0, bv0};
            acc[mt][1] = (floatx4){bv1, bv1, bv1, bv1};
            acc[mt][2] = (floatx4){bv2, bv2, bv2, bv2};
            acc[mt][3] = (floatx4){bv3, bv3, bv3, bv3};
        }
    }

    for (int kc = 0; kc < 10; kc++) {
        // ---- produce this thread's 8 bf16 F-values (global loads) ----
        uint4 raw = {0, 0, 0, 0};
        if (svalid) {
            if (kc < 4) {
                raw = ld8_bf16(x, snode * 128 + kc * 32 + skq * 8, f32);
            } else if (kc < 6) {
                raw = ld8_bf16(h, snode * 64 + (kc - 4) * 32 + skq * 8, f32);
            } else if (kc < 8) {
                const float* p = Tx1 + snode * 64 + (kc - 6) * 32 + skq * 8;
                float4 a = *(const float4*)p, b = *(const float4*)(p + 4);
                float f[8] = {a.x, a.y, a.z, a.w, b.x, b.y, b.z, b.w};
                raw = packf8(f);
            } else {
                int off = snode * 64 + (kc - 8) * 32 + skq * 8;
                const float* pa = agg2 + off;
                float4 a = *(const float4*)pa, b = *(const float4*)(pa + 4);
                float av[8] = {a.x, a.y, a.z, a.w, b.x, b.y, b.z, b.w};
                float hv[8];
                if (f32) {
                    const float* ph = (const float*)h + off;
                    float4 h0_ = *(const float4*)ph, h1_ = *(const float4*)(ph + 4);
                    hv[0]=h0_.x; hv[1]=h0_.y; hv[2]=h0_.z; hv[3]=h0_.w;
                    hv[4]=h1_.x; hv[5]=h1_.y; hv[6]=h1_.z; hv[7]=h1_.w;
                } else {
                    uint4 hr = *(const uint4*)((const ushort*)h + off);
                    uint u[4] = {hr.x, hr.y, hr.z, hr.w};
#pragma unroll
                    for (int q = 0; q < 4; q++) {
                        hv[2*q]   = b2f_raw((ushort)(u[q] & 0xffff));
                        hv[2*q+1] = b2f_raw((ushort)(u[q] >> 16));
                    }
                }
                float f[8];
#pragma unroll
                for (int j = 0; j < 8; j++) f[j] = 2.f * av[j] - hv[j];
                raw = packf8(f);
            }
        }
        // ---- B fragments for this chunk (global, L2-resident) ----
        short8 bF[4];
#pragma unroll
        for (int g = 0; g < 4; g++)
            bF[g] = *(const short8*)&Wf[((kc * 16 + w * 4 + g) * 64 + lane) * 8];

        __syncthreads();                 // prior chunk's reads complete
        *sdst = raw;
        __syncthreads();                 // staging visible

        short8 aF[4];
#pragma unroll
        for (int mt = 0; mt < 4; mt++)
            aF[mt] = *(const short8*)&As[(mt * 64 + lane) * 8];
#pragma unroll
        for (int mt = 0; mt < 4; mt++)
#pragma unroll
            for (int g = 0; g < 4; g++)
                acc[mt][g] = __builtin_amdgcn_mfma_f32_16x16x32_bf16(
                    aF[mt], bF[g], acc[mt][g], 0, 0, 0);
    }

    // ---- LSTM epilogue, fully in-register (perm put all 4 gates here) ----
    const int cc = w * 16 + (lane & 15);
#pragma unroll
    for (int mt = 0; mt < 4; mt++) {
        const int m0 = mt * 16 + ((lane >> 4) * 4);
#pragma unroll
        for (int r = 0; r < 4; r++) {
            int ml = m0 + r;
            int node = base + ml;
            float gi = sigmoidf(acc[mt][0][r]);
            float gf = sigmoidf(acc[mt][1][r]);
            float gt = tanh_fast(acc[mt][2][r]);
            float go = sigmoidf(acc[mt][3][r]);
            float cv = (node < NN) ? ldin(cin, node * 64 + cc, f32) : 0.f;
            float c0 = gf * cv + gi * gt;
            float h0v = go * tanh_fast(c0);
            if (node < NN) {
                c0o[node * 64 + cc] = c0;
                h0o[node * 64 + cc] = h0v;
            }
            Hs[ml * 72 + cc] = f2bu(fmaxf(h0v, 0.f));
        }
    }
    __syncthreads();

    // ---- fused out = relu(h0) @ Wl + bl (8 MFMA per wave) ----
    float blv = ldin(bl, w * 16 + (lane & 15), f32);
    floatx4 oacc[4];
#pragma unroll
    for (int mt = 0; mt < 4; mt++) oacc[mt] = (floatx4){blv, blv, blv, blv};
#pragma unroll
    for (int kc2 = 0; kc2 < 2; kc2++) {
        short8 bW = *(const short8*)&WlF[((kc2 * 4 + w) * 64 + lane) * 8];
#pragma unroll
        for (int mt = 0; mt < 4; mt++) {
            short8 aH = *(const short8*)&Hs[(mt * 16 + (lane & 15)) * 72
                                            + kc2 * 32 + (lane >> 4) * 8];
            oacc[mt] = __builtin_amdgcn_mfma_f32_16x16x32_bf16(
                aH, bW, oacc[mt], 0, 0, 0);
        }
    }
#pragma unroll
    for (int mt = 0; mt < 4; mt++) {
        const int m0 = mt * 16 + ((lane >> 4) * 4);
#pragma unroll
        for (int r = 0; r < 4; r++) {
            int node = base + m0 + r;
            if (node < NN)
                outF[node * 64 + w * 16 + (lane & 15)] = oacc[mt][r];
        }
    }
}

extern "C" void kernel_launch(void* const* d_in, const int* in_sizes, int n_in,
                              void* d_out, int out_size, void* d_ws, size_t ws_size,
                              hipStream_t stream) {
    const void* x     = d_in[0];
    const int*  ei    = (const int*)d_in[1];
    const void* ew    = d_in[2];
    const void* h     = d_in[3];
    const void* c     = d_in[4];
    const void* Wx    = d_in[5];
    const void* bg    = d_in[6];
    const void* theta = d_in[7];
    const void* convb = d_in[8];
    const void* Wl    = d_in[9];
    const void* bl    = d_in[10];
    (void)in_sizes; (void)n_in; (void)out_size; (void)ws_size;

    // ws layout (4B words) — ~1.78 MB total
    float*  ws     = (float*)d_ws;
    int*    flag   = (int*)ws;                 // 64
    float*  deg    = ws + 64;                  // 100000 (-> dinv in place)
    int*    cnt    = (int*)(ws + 100064);      // 100000
    int*    rowptr = (int*)(ws + 200064);      // 100001 (pad to 100064)
    int*    wptr   = (int*)(ws + 300128);      // 100000
    float*  biasP  = ws + 400128;              // 256
    ushort* Wf     = (ushort*)(ws + 400384);   // 81920 ushort = 40960 words
    ushort* WlF    = (ushort*)(ws + 441344);   // 4096 ushort = 2048 words

    // d_out FP32: out [0,6.4M) | h0 [6.4M,12.8M) | c0 [12.8M,19.2M)
    float* outF = (float*)d_out;
    float* h0o  = outF + (size_t)NN * 64;
    float* c0o  = outF + (size_t)2 * NN * 64;
    float* Tx1f = outF;          // alias (same-row fp32 mapping)
    int2*  csr  = (int2*)h0o;    // read-complete before k_gates
    float* agg2 = c0o;           // alias (same-row fp32 mapping)
    // scan scratch: dead space of h0o region beyond csr (csr = 3.2M ints,
    // region = 6.4M ints); consumed before k_fill writes csr.
    int*   bsum = (int*)h0o + 3200000;   // 98 used
    int*   boff = bsum + 128;            // 98 used

    k_sniff<<<1, 256, 0, stream>>>(x, flag);
    hipMemsetAsync(deg, 0, (size_t)200000 * 4, stream);  // deg + cnt

    k_deghist<<<NE / 256, 256, 0, stream>>>(ei, ew, deg, cnt, flag);
    k_dinv<<<(NN + 255) / 256, 256, 0, stream>>>(deg);
    k_scan1<<<SCANB, 256, 0, stream>>>(cnt, bsum);
    k_scan2<<<1, 128, 0, stream>>>(bsum, boff, rowptr);
    k_scan3<<<SCANB, 256, 0, stream>>>(cnt, boff, rowptr, wptr);
    k_fill<<<NE / 256, 256, 0, stream>>>(ei, ew, deg, wptr, csr, flag);
    k_wcat<<<336, 256, 0, stream>>>(Wx, theta, bg, convb, Wl, Wf, biasP, WlF, flag);

    k_gath<true ><<<25000, 256, 0, stream>>>(rowptr, csr, h,    Tx1f, flag);
    k_gath<false><<<25000, 256, 0, stream>>>(rowptr, csr, Tx1f, agg2, flag);

    k_gates<<<(NN + 63) / 64, 256, 0, stream>>>(x, h, c, Tx1f, agg2,
                                                Wf, biasP, WlF, bl,
                                                outF, h0o, c0o, flag);
}

// Round 2
// 617.543 us; speedup vs baseline: 1.4729x; 1.1284x over previous
//
#include <hip/hip_runtime.h>
#include <hip/hip_bf16.h>

#define NN 100000
#define NE 1600000
#define INDIM 128
#define HID 64
#define CAP 31          // fixed CSR slots per node (mean in-degree = 16)
#define OVCAP 66000     // overflow entries (expected ~40 for this input)

typedef __hip_bfloat16 bf16;
typedef unsigned short ushort;
typedef unsigned int uint;
typedef __attribute__((ext_vector_type(8))) short short8;
typedef __attribute__((ext_vector_type(4))) float floatx4;

__device__ __forceinline__ float b2f(bf16 v) { return __bfloat162float(v); }
__device__ __forceinline__ float b2f_raw(ushort u) { return __uint_as_float(((uint)u) << 16); }
__device__ __forceinline__ ushort f2bu(float v) {
    bf16 t = __float2bfloat16(v);
    return *reinterpret_cast<ushort*>(&t);
}
// flag-aware input load: f32==1 -> fp32 tensor, else bf16 tensor
__device__ __forceinline__ float ldin(const void* p, int i, int f32) {
    return f32 ? ((const float*)p)[i] : b2f(((const bf16*)p)[i]);
}
__device__ __forceinline__ float sigmoidf(float x) { return 1.f / (1.f + __expf(-x)); }
__device__ __forceinline__ float tanh_fast(float x) {
    float e = __expf(2.f * x);
    return 1.f - 2.f / (e + 1.f);
}
__device__ __forceinline__ uint4 packf8(const float* f) {
    uint4 u;
    u.x = f2bu(f[0]) | ((uint)f2bu(f[1]) << 16);
    u.y = f2bu(f[2]) | ((uint)f2bu(f[3]) << 16);
    u.z = f2bu(f[4]) | ((uint)f2bu(f[5]) << 16);
    u.w = f2bu(f[6]) | ((uint)f2bu(f[7]) << 16);
    return u;
}
// 8 consecutive elements of a (bf16|fp32) tensor as packed bf16
__device__ __forceinline__ uint4 ld8_bf16(const void* p, int off, int f32) {
    if (!f32) return *(const uint4*)((const ushort*)p + off);
    const float* q = (const float*)p + off;
    float4 a = *(const float4*)q, b = *(const float4*)(q + 4);
    float f[8] = {a.x, a.y, a.z, a.w, b.x, b.y, b.z, b.w};
    return packf8(f);
}

// ---------------- dtype sniffer ----------------------------------------
__global__ void k_sniff(const void* __restrict__ x, int* __restrict__ flag) {
    __shared__ int cnt;
    if (threadIdx.x == 0) cnt = 0;
    __syncthreads();
    const bf16* p = (const bf16*)x;
    int bad = 0;
    for (int i = threadIdx.x; i < 8192; i += 256) {
        float v = b2f(p[i]);
        if (!(fabsf(v) < 1e6f)) bad++;
    }
    atomicAdd(&cnt, bad);
    __syncthreads();
    if (threadIdx.x == 0) flag[0] = (cnt > 32) ? 1 : 0;
}

// ---------------- single pass: deg atomic + fixed-cap CSR fill ---------
// csr0[dst*CAP + pos] = {src, raw w}; overflow -> (ovfD,ovfS,ovfW) list.
// dinv scaling deferred to the gather kernels.
__global__ void k_fill3(const int* __restrict__ ei, const void* __restrict__ ew,
                        float* __restrict__ deg, int* __restrict__ pcnt,
                        int2* __restrict__ csr0, int* __restrict__ ovfcnt,
                        int* __restrict__ ovfD, int* __restrict__ ovfS,
                        int* __restrict__ ovfW, const int* __restrict__ flagp) {
    const int f32 = flagp[0];
    int e = blockIdx.x * 256 + threadIdx.x;   // grid exactly NE
    int src = ei[e], dst = ei[NE + e];
    if (src == dst) return;
    float w = ldin(ew, e, f32);
    atomicAdd(deg + src, w);
    int pos = atomicAdd(pcnt + dst, 1);
    if (pos < CAP) {
        int2 p; p.x = src; p.y = __float_as_int(w);
        csr0[(size_t)dst * CAP + pos] = p;
    } else {
        int op = atomicAdd(ovfcnt, 1);
        if (op < OVCAP) {
            ovfD[op] = dst; ovfS[op] = src; ovfW[op] = __float_as_int(w);
        }
    }
}

__global__ void k_dinv(float* __restrict__ buf) {
    int n = blockIdx.x * 256 + threadIdx.x;
    if (n < NN) { float d = buf[n]; buf[n] = d > 0.f ? rsqrtf(d) : 0.f; }
}

// ---------------- gather SpMM: one wave per dst, register accumulate ---
// out[dst] = -dinv[dst] * sum_e dinv[src_e] * w_e * z[src_e]
template<bool BF16IN>
__global__ __launch_bounds__(256)
void k_gath(const int* __restrict__ pcnt, const float* __restrict__ dinv,
            const int2* __restrict__ csr0, const void* __restrict__ zin,
            float* __restrict__ outv, const int* __restrict__ flagp) {
    const int f32 = flagp[0];
    int n = (blockIdx.x * 256 + threadIdx.x) >> 6;   // dst node
    int lane = threadIdx.x & 63;
    if (n >= NN) return;
    int cnt = pcnt[n]; if (cnt > CAP) cnt = CAP;
    const int2* row = csr0 + (size_t)n * CAP;
    float acc = 0.f;
    int i = 0;
    for (; i + 1 < cnt; i += 2) {
        int2 p0 = row[i], p1 = row[i + 1];
        float s0 = dinv[p0.x] * __int_as_float(p0.y);
        float s1 = dinv[p1.x] * __int_as_float(p1.y);
        float z0 = BF16IN ? ldin(zin, p0.x * 64 + lane, f32)
                          : ((const float*)zin)[p0.x * 64 + lane];
        float z1 = BF16IN ? ldin(zin, p1.x * 64 + lane, f32)
                          : ((const float*)zin)[p1.x * 64 + lane];
        acc = fmaf(s0, z0, acc);
        acc = fmaf(s1, z1, acc);
    }
    if (i < cnt) {
        int2 p0 = row[i];
        float s0 = dinv[p0.x] * __int_as_float(p0.y);
        float z0 = BF16IN ? ldin(zin, p0.x * 64 + lane, f32)
                          : ((const float*)zin)[p0.x * 64 + lane];
        acc = fmaf(s0, z0, acc);
    }
    outv[n * 64 + lane] = -dinv[n] * acc;
}

// ---------------- apply overflow edges (rare): atomic add into outv ----
template<bool BF16IN>
__global__ void k_ovf(const int* __restrict__ ovfcnt, const int* __restrict__ ovfD,
                      const int* __restrict__ ovfS, const int* __restrict__ ovfW,
                      const float* __restrict__ dinv, const void* __restrict__ zin,
                      float* __restrict__ outv, const int* __restrict__ flagp) {
    const int f32 = flagp[0];
    int nov = ovfcnt[0]; if (nov > OVCAP) nov = OVCAP;
    int wid = (blockIdx.x * 256 + threadIdx.x) >> 6;
    int lane = threadIdx.x & 63;
    int nw = gridDim.x * 4;
    for (int i = wid; i < nov; i += nw) {
        int dst = ovfD[i], src = ovfS[i];
        float w = __int_as_float(ovfW[i]);
        float s = -dinv[dst] * dinv[src] * w;
        float z = BF16IN ? ldin(zin, src * 64 + lane, f32)
                         : ((const float*)zin)[src * 64 + lane];
        atomicAdd(outv + (size_t)dst * 64 + lane, s * z);
    }
}

// ---------------- pre-swizzle weights into MFMA fragment order ---------
// Wf: [kc 0..9][t 0..15][lane 0..63][j 0..7] bf16, element =
//     W[r = kc*32 + (lane>>4)*8 + j][o = 16t + (lane&15)] with column perm
//     o = 16t+(l&15): gate g = t&3, cc = (t>>2)*16 + (lane&15)
// WlF: [kc2 0..1][t 0..3][lane][j], Wl[k = kc2*32+(l>>4)*8+j][n = 16t+(l&15)]
// biasP[o]: permuted bias
__global__ void k_wcat(const void* __restrict__ Wx, const void* __restrict__ theta,
                       const void* __restrict__ bg, const void* __restrict__ convb,
                       const void* __restrict__ Wl,
                       ushort* __restrict__ Wf, float* __restrict__ biasP,
                       ushort* __restrict__ WlF, const int* __restrict__ flagp) {
    const int f32 = flagp[0];
    int gid = blockIdx.x * 256 + threadIdx.x;   // 336 blocks * 256 = 86016
    if (gid < 81920) {
        int j = gid & 7, l = (gid >> 3) & 63, tile = gid >> 9;
        int kc = tile >> 4, t = tile & 15;
        int r = kc * 32 + ((l >> 4) * 8) + j;
        int g = t & 3;
        int cc = (t >> 2) * 16 + (l & 15);
        float v;
        if (r < 128) {
            v = ldin(Wx, (g * 128 + r) * 64 + cc, f32);
        } else {
            int k3 = (r - 128) >> 6, rr = (r - 128) & 63;
            v = ldin(theta, ((g * 3 + k3) * 64 + rr) * 64 + cc, f32);
        }
        Wf[gid] = f2bu(v);
        if (gid < 256) {
            int o = gid;
            int gg = (o >> 4) & 3;
            int cc2 = (o >> 6) * 16 + (o & 15);
            biasP[o] = ldin(bg, gg * 64 + cc2, f32) + ldin(convb, gg * 64 + cc2, f32);
        }
    } else {
        int gid2 = gid - 81920;                  // [0, 4096)
        int j = gid2 & 7, l = (gid2 >> 3) & 63, tile2 = gid2 >> 9;
        int kc2 = tile2 >> 2, t = tile2 & 3;
        int k = kc2 * 32 + ((l >> 4) * 8) + j;
        int n = t * 16 + (l & 15);
        WlF[gid2] = f2bu(ldin(Wl, k * 64 + n, f32));
    }
}

// ---------------- MFMA gate GEMM [64 nodes x 256 cols] + LSTM + out ----
// F rows: 0-127 x | 128-191 h | 192-255 Tx1 | 256-319 (2*agg2 - h)
// Aliasing: Tx1 lives in `out` fp32 region, agg2 in `c0` fp32 region —
// same-dtype same-row mapping, blocks only touch their own 64-node slab,
// all reads precede all writes within the block. Safe.
__global__ __launch_bounds__(256)
void k_gates(const void* __restrict__ x, const void* __restrict__ h,
             const void* __restrict__ cin,
             const float* __restrict__ Tx1, const float* __restrict__ agg2,
             const ushort* __restrict__ Wf, const float* __restrict__ biasP,
             const ushort* __restrict__ WlF, const void* __restrict__ bl,
             float* __restrict__ outF, float* __restrict__ h0o,
             float* __restrict__ c0o, const int* __restrict__ flagp) {
    const int f32 = flagp[0];
    __shared__ ushort As[4 * 64 * 8];    // 4 KB, A fragments for one 64x32 chunk
    __shared__ ushort Hs[64 * 72];       // 9.2 KB, relu(h0) bf16, padded stride 72
    const int tid = threadIdx.x;
    const int lane = tid & 63;
    const int w = tid >> 6;              // wave 0..3
    const int base = blockIdx.x * 64;
    // staging role: thread -> (node sm, k-quad skq)
    const int sm = tid & 63;
    const int skq = tid >> 6;
    const int snode = base + sm;
    const bool svalid = snode < NN;
    uint4* sdst = (uint4*)&As[(((sm >> 4) * 64) + ((sm & 15) + 16 * skq)) * 8];

    floatx4 acc[4][4];                   // [m-tile][gate]
    {
        float bv0 = biasP[w * 64 + 0 * 16 + (lane & 15)];
        float bv1 = biasP[w * 64 + 1 * 16 + (lane & 15)];
        float bv2 = biasP[w * 64 + 2 * 16 + (lane & 15)];
        float bv3 = biasP[w * 64 + 3 * 16 + (lane & 15)];
#pragma unroll
        for (int mt = 0; mt < 4; mt++) {
            acc[mt][0] = (floatx4){bv0, bv0, bv0, bv0};
            acc[mt][1] = (floatx4){bv1, bv1, bv1, bv1};
            acc[mt][2] = (floatx4){bv2, bv2, bv2, bv2};
            acc[mt][3] = (floatx4){bv3, bv3, bv3, bv3};
        }
    }

    for (int kc = 0; kc < 10; kc++) {
        // ---- produce this thread's 8 bf16 F-values (global loads) ----
        uint4 raw = {0, 0, 0, 0};
        if (svalid) {
            if (kc < 4) {
                raw = ld8_bf16(x, snode * 128 + kc * 32 + skq * 8, f32);
            } else if (kc < 6) {
                raw = ld8_bf16(h, snode * 64 + (kc - 4) * 32 + skq * 8, f32);
            } else if (kc < 8) {
                const float* p = Tx1 + snode * 64 + (kc - 6) * 32 + skq * 8;
                float4 a = *(const float4*)p, b = *(const float4*)(p + 4);
                float f[8] = {a.x, a.y, a.z, a.w, b.x, b.y, b.z, b.w};
                raw = packf8(f);
            } else {
                int off = snode * 64 + (kc - 8) * 32 + skq * 8;
                const float* pa = agg2 + off;
                float4 a = *(const float4*)pa, b = *(const float4*)(pa + 4);
                float av[8] = {a.x, a.y, a.z, a.w, b.x, b.y, b.z, b.w};
                float hv[8];
                if (f32) {
                    const float* ph = (const float*)h + off;
                    float4 h0_ = *(const float4*)ph, h1_ = *(const float4*)(ph + 4);
                    hv[0]=h0_.x; hv[1]=h0_.y; hv[2]=h0_.z; hv[3]=h0_.w;
                    hv[4]=h1_.x; hv[5]=h1_.y; hv[6]=h1_.z; hv[7]=h1_.w;
                } else {
                    uint4 hr = *(const uint4*)((const ushort*)h + off);
                    uint u[4] = {hr.x, hr.y, hr.z, hr.w};
#pragma unroll
                    for (int q = 0; q < 4; q++) {
                        hv[2*q]   = b2f_raw((ushort)(u[q] & 0xffff));
                        hv[2*q+1] = b2f_raw((ushort)(u[q] >> 16));
                    }
                }
                float f[8];
#pragma unroll
                for (int j = 0; j < 8; j++) f[j] = 2.f * av[j] - hv[j];
                raw = packf8(f);
            }
        }
        // ---- B fragments for this chunk (global, L2-resident) ----
        short8 bF[4];
#pragma unroll
        for (int g = 0; g < 4; g++)
            bF[g] = *(const short8*)&Wf[((kc * 16 + w * 4 + g) * 64 + lane) * 8];

        __syncthreads();                 // prior chunk's reads complete
        *sdst = raw;
        __syncthreads();                 // staging visible

        short8 aF[4];
#pragma unroll
        for (int mt = 0; mt < 4; mt++)
            aF[mt] = *(const short8*)&As[(mt * 64 + lane) * 8];
#pragma unroll
        for (int mt = 0; mt < 4; mt++)
#pragma unroll
            for (int g = 0; g < 4; g++)
                acc[mt][g] = __builtin_amdgcn_mfma_f32_16x16x32_bf16(
                    aF[mt], bF[g], acc[mt][g], 0, 0, 0);
    }

    // ---- LSTM epilogue, fully in-register (perm put all 4 gates here) ----
    const int cc = w * 16 + (lane & 15);
#pragma unroll
    for (int mt = 0; mt < 4; mt++) {
        const int m0 = mt * 16 + ((lane >> 4) * 4);
#pragma unroll
        for (int r = 0; r < 4; r++) {
            int ml = m0 + r;
            int node = base + ml;
            float gi = sigmoidf(acc[mt][0][r]);
            float gf = sigmoidf(acc[mt][1][r]);
            float gt = tanh_fast(acc[mt][2][r]);
            float go = sigmoidf(acc[mt][3][r]);
            float cv = (node < NN) ? ldin(cin, node * 64 + cc, f32) : 0.f;
            float c0 = gf * cv + gi * gt;
            float h0v = go * tanh_fast(c0);
            if (node < NN) {
                c0o[node * 64 + cc] = c0;
                h0o[node * 64 + cc] = h0v;
            }
            Hs[ml * 72 + cc] = f2bu(fmaxf(h0v, 0.f));
        }
    }
    __syncthreads();

    // ---- fused out = relu(h0) @ Wl + bl (8 MFMA per wave) ----
    float blv = ldin(bl, w * 16 + (lane & 15), f32);
    floatx4 oacc[4];
#pragma unroll
    for (int mt = 0; mt < 4; mt++) oacc[mt] = (floatx4){blv, blv, blv, blv};
#pragma unroll
    for (int kc2 = 0; kc2 < 2; kc2++) {
        short8 bW = *(const short8*)&WlF[((kc2 * 4 + w) * 64 + lane) * 8];
#pragma unroll
        for (int mt = 0; mt < 4; mt++) {
            short8 aH = *(const short8*)&Hs[(mt * 16 + (lane & 15)) * 72
                                            + kc2 * 32 + (lane >> 4) * 8];
            oacc[mt] = __builtin_amdgcn_mfma_f32_16x16x32_bf16(
                aH, bW, oacc[mt], 0, 0, 0);
        }
    }
#pragma unroll
    for (int mt = 0; mt < 4; mt++) {
        const int m0 = mt * 16 + ((lane >> 4) * 4);
#pragma unroll
        for (int r = 0; r < 4; r++) {
            int node = base + m0 + r;
            if (node < NN)
                outF[node * 64 + w * 16 + (lane & 15)] = oacc[mt][r];
        }
    }
}

extern "C" void kernel_launch(void* const* d_in, const int* in_sizes, int n_in,
                              void* d_out, int out_size, void* d_ws, size_t ws_size,
                              hipStream_t stream) {
    const void* x     = d_in[0];
    const int*  ei    = (const int*)d_in[1];
    const void* ew    = d_in[2];
    const void* h     = d_in[3];
    const void* c     = d_in[4];
    const void* Wx    = d_in[5];
    const void* bg    = d_in[6];
    const void* theta = d_in[7];
    const void* convb = d_in[8];
    const void* Wl    = d_in[9];
    const void* bl    = d_in[10];
    (void)in_sizes; (void)n_in; (void)out_size; (void)ws_size;

    // ws layout (4B words) — ~1.78 MB total
    float*  ws     = (float*)d_ws;
    int*    flag   = (int*)ws;                 // 64
    float*  deg    = ws + 64;                  // 100000 (-> dinv in place)
    int*    pcnt   = (int*)(ws + 100064);      // 100000
    int*    ovfcnt = (int*)(ws + 200064);      // 1 (+pad)
    float*  biasP  = ws + 400128;              // 256
    ushort* Wf     = (ushort*)(ws + 400384);   // 81920 ushort = 40960 words
    ushort* WlF    = (ushort*)(ws + 441344);   // 4096 ushort = 2048 words

    // d_out FP32: out [0,6.4M) | h0 [6.4M,12.8M) | c0 [12.8M,19.2M)  (words)
    float* outF = (float*)d_out;
    float* h0o  = outF + (size_t)NN * 64;
    float* c0o  = outF + (size_t)2 * NN * 64;
    float* Tx1f = outF;          // alias (same-row fp32 mapping)
    float* agg2 = c0o;           // alias (same-row fp32 mapping)
    // CSR (fixed cap) + overflow live in the h0 region (6.4M words):
    //   csr0 = 100000*31 int2 = 6.2M words; overflow lists in the last 200K.
    int2* csr0 = (int2*)h0o;
    int*  ovfD = (int*)h0o + 6200000;   // 66000
    int*  ovfS = ovfD + 66000;
    int*  ovfW = ovfS + 66000;

    k_sniff<<<1, 256, 0, stream>>>(x, flag);
    hipMemsetAsync(deg, 0, (size_t)200080 * 4, stream);  // deg + pcnt + ovfcnt

    k_fill3<<<NE / 256, 256, 0, stream>>>(ei, ew, deg, pcnt, csr0,
                                          ovfcnt, ovfD, ovfS, ovfW, flag);
    k_dinv<<<(NN + 255) / 256, 256, 0, stream>>>(deg);
    k_wcat<<<336, 256, 0, stream>>>(Wx, theta, bg, convb, Wl, Wf, biasP, WlF, flag);

    k_gath<true ><<<25000, 256, 0, stream>>>(pcnt, deg, csr0, h,    Tx1f, flag);
    k_ovf<true ><<<64, 256, 0, stream>>>(ovfcnt, ovfD, ovfS, ovfW, deg, h,    Tx1f, flag);
    k_gath<false><<<25000, 256, 0, stream>>>(pcnt, deg, csr0, Tx1f, agg2, flag);
    k_ovf<false><<<64, 256, 0, stream>>>(ovfcnt, ovfD, ovfS, ovfW, deg, Tx1f, agg2, flag);

    k_gates<<<(NN + 63) / 64, 256, 0, stream>>>(x, h, c, Tx1f, agg2,
                                                Wf, biasP, WlF, bl,
                                                outF, h0o, c0o, flag);
}

// Round 3
// 580.172 us; speedup vs baseline: 1.5678x; 1.0644x over previous
//
#include <hip/hip_runtime.h>
#include <hip/hip_bf16.h>

#define NN 100000
#define NE 1600000
#define INDIM 128
#define HID 64
#define CAP 31          // fixed CSR slots per node (mean in-degree = 16)
#define OVCAP 66000     // overflow entries (expected ~40 for this input)

typedef __hip_bfloat16 bf16;
typedef unsigned short ushort;
typedef unsigned int uint;
typedef __attribute__((ext_vector_type(8))) short short8;
typedef __attribute__((ext_vector_type(4))) float floatx4;

__device__ __forceinline__ float b2f(bf16 v) { return __bfloat162float(v); }
__device__ __forceinline__ float b2f_raw(ushort u) { return __uint_as_float(((uint)u) << 16); }
__device__ __forceinline__ ushort f2bu(float v) {
    bf16 t = __float2bfloat16(v);
    return *reinterpret_cast<ushort*>(&t);
}
// flag-aware input load: f32==1 -> fp32 tensor, else bf16 tensor
__device__ __forceinline__ float ldin(const void* p, int i, int f32) {
    return f32 ? ((const float*)p)[i] : b2f(((const bf16*)p)[i]);
}
__device__ __forceinline__ float sigmoidf(float x) { return 1.f / (1.f + __expf(-x)); }
__device__ __forceinline__ float tanh_fast(float x) {
    float e = __expf(2.f * x);
    return 1.f - 2.f / (e + 1.f);
}
__device__ __forceinline__ uint4 packf8(const float* f) {
    uint4 u;
    u.x = f2bu(f[0]) | ((uint)f2bu(f[1]) << 16);
    u.y = f2bu(f[2]) | ((uint)f2bu(f[3]) << 16);
    u.z = f2bu(f[4]) | ((uint)f2bu(f[5]) << 16);
    u.w = f2bu(f[6]) | ((uint)f2bu(f[7]) << 16);
    return u;
}
// 8 consecutive elements of a (bf16|fp32) tensor as packed bf16
__device__ __forceinline__ uint4 ld8_bf16(const void* p, int off, int f32) {
    if (!f32) return *(const uint4*)((const ushort*)p + off);
    const float* q = (const float*)p + off;
    float4 a = *(const float4*)q, b = *(const float4*)(q + 4);
    float f[8] = {a.x, a.y, a.z, a.w, b.x, b.y, b.z, b.w};
    return packf8(f);
}
// 4 consecutive edge weights
__device__ __forceinline__ void ld4w(const void* ew, int e0, int f32, float* w) {
    if (f32) {
        float4 v = *(const float4*)((const float*)ew + e0);
        w[0] = v.x; w[1] = v.y; w[2] = v.z; w[3] = v.w;
    } else {
        uint2 v = *(const uint2*)((const ushort*)ew + e0);
        w[0] = b2f_raw((ushort)(v.x & 0xffff)); w[1] = b2f_raw((ushort)(v.x >> 16));
        w[2] = b2f_raw((ushort)(v.y & 0xffff)); w[3] = b2f_raw((ushort)(v.y >> 16));
    }
}

// ---------------- dtype sniffer ----------------------------------------
__global__ void k_sniff(const void* __restrict__ x, int* __restrict__ flag) {
    __shared__ int cnt;
    if (threadIdx.x == 0) cnt = 0;
    __syncthreads();
    const bf16* p = (const bf16*)x;
    int bad = 0;
    for (int i = threadIdx.x; i < 8192; i += 256) {
        float v = b2f(p[i]);
        if (!(fabsf(v) < 1e6f)) bad++;
    }
    atomicAdd(&cnt, bad);
    __syncthreads();
    if (threadIdx.x == 0) flag[0] = (cnt > 32) ? 1 : 0;
}

// ---------------- single pass: deg atomic + fixed-cap CSR fill ---------
// 4 edges per thread: vector edge loads, batched atomics for ILP.
// csr0[dst*CAP + pos] = {src, raw w}; overflow -> (ovfD,ovfS,ovfW) list.
// dinv scaling deferred to the gather kernels.
__global__ __launch_bounds__(256)
void k_fill3(const int* __restrict__ ei, const void* __restrict__ ew,
             float* __restrict__ deg, int* __restrict__ pcnt,
             int2* __restrict__ csr0, int* __restrict__ ovfcnt,
             int* __restrict__ ovfD, int* __restrict__ ovfS,
             int* __restrict__ ovfW, const int* __restrict__ flagp) {
    const int f32 = flagp[0];
    int e0 = (blockIdx.x * 256 + threadIdx.x) * 4;
    if (e0 >= NE) return;
    int4 s4 = *(const int4*)(ei + e0);
    int4 d4 = *(const int4*)(ei + NE + e0);
    float w[4];
    ld4w(ew, e0, f32, w);
    int s[4] = {s4.x, s4.y, s4.z, s4.w};
    int d[4] = {d4.x, d4.y, d4.z, d4.w};
    bool act[4];
#pragma unroll
    for (int j = 0; j < 4; j++) act[j] = (s[j] != d[j]);
#pragma unroll
    for (int j = 0; j < 4; j++)
        if (act[j]) atomicAdd(deg + s[j], w[j]);    // fire-and-forget
    int pos[4];
#pragma unroll
    for (int j = 0; j < 4; j++)
        pos[j] = act[j] ? atomicAdd(pcnt + d[j], 1) : 0x7fffffff;
#pragma unroll
    for (int j = 0; j < 4; j++) {
        if (!act[j]) continue;
        if (pos[j] < CAP) {
            int2 p; p.x = s[j]; p.y = __float_as_int(w[j]);
            csr0[(size_t)d[j] * CAP + pos[j]] = p;
        } else {
            int op = atomicAdd(ovfcnt, 1);
            if (op < OVCAP) {
                ovfD[op] = d[j]; ovfS[op] = s[j]; ovfW[op] = __float_as_int(w[j]);
            }
        }
    }
}

__global__ void k_dinv(float* __restrict__ buf) {
    int n = blockIdx.x * 256 + threadIdx.x;
    if (n < NN) { float d = buf[n]; buf[n] = d > 0.f ? rsqrtf(d) : 0.f; }
}

// ---------------- gather SpMM: one wave per dst, register accumulate ---
// out[dst] = -dinv[dst] * sum_e dinv[src_e] * w_e * z[src_e]
// MODE 0: z = h (flag dtype, stride 64)  -> out bf16, row stride 128 elems
// MODE 1: z = bf16 stride-128 rows       -> out fp32, stride 64
// Overflow edges (cnt > CAP) are folded in by scanning the tiny ovf list.
template<int MODE>
__global__ __launch_bounds__(256)
void k_gath(const int* __restrict__ pcnt, const float* __restrict__ dinv,
            const int2* __restrict__ csr0, const void* __restrict__ zin,
            void* __restrict__ outv,
            const int* __restrict__ ovfcnt, const int* __restrict__ ovfD,
            const int* __restrict__ ovfS, const int* __restrict__ ovfW,
            const int* __restrict__ flagp) {
    const int f32 = flagp[0];
    int n = (blockIdx.x * 256 + threadIdx.x) >> 6;   // dst node
    int lane = threadIdx.x & 63;
    if (n >= NN) return;
    int cntraw = pcnt[n];
    int cnt = cntraw > CAP ? CAP : cntraw;
    const int2* row = csr0 + (size_t)n * CAP;
    float acc = 0.f;
    int i = 0;
#define ZLD(sidx) (MODE == 0 ? ldin(zin, (sidx) * 64 + lane, f32) \
                             : b2f_raw(((const ushort*)zin)[(sidx) * 128 + lane]))
    for (; i + 3 < cnt; i += 4) {
        int2 p0 = row[i], p1 = row[i + 1], p2 = row[i + 2], p3 = row[i + 3];
        float z0 = ZLD(p0.x), z1 = ZLD(p1.x), z2 = ZLD(p2.x), z3 = ZLD(p3.x);
        acc = fmaf(dinv[p0.x] * __int_as_float(p0.y), z0, acc);
        acc = fmaf(dinv[p1.x] * __int_as_float(p1.y), z1, acc);
        acc = fmaf(dinv[p2.x] * __int_as_float(p2.y), z2, acc);
        acc = fmaf(dinv[p3.x] * __int_as_float(p3.y), z3, acc);
    }
    for (; i < cnt; i++) {
        int2 p0 = row[i];
        float z0 = ZLD(p0.x);
        acc = fmaf(dinv[p0.x] * __int_as_float(p0.y), z0, acc);
    }
    if (cntraw > CAP) {                      // rare (~30 nodes): scan ovf list
        int nov = ovfcnt[0]; if (nov > OVCAP) nov = OVCAP;
        for (int k = 0; k < nov; k++) {
            if (ovfD[k] == n) {
                int src = ovfS[k];
                float z = ZLD(src);
                acc = fmaf(dinv[src] * __int_as_float(ovfW[k]), z, acc);
            }
        }
    }
#undef ZLD
    float r = -dinv[n] * acc;
    if (MODE == 0) ((ushort*)outv)[(size_t)n * 128 + lane] = f2bu(r);
    else           ((float*)outv)[(size_t)n * 64 + lane] = r;
}

// ---------------- pre-swizzle weights into MFMA fragment order ---------
// Wf: [kc 0..9][t 0..15][lane 0..63][j 0..7] bf16, element =
//     W[r = kc*32 + (lane>>4)*8 + j][o = 16t + (lane&15)] with column perm
//     o = 16t+(l&15): gate g = t&3, cc = (t>>2)*16 + (lane&15)
// WlF: [kc2 0..1][t 0..3][lane][j], Wl[k = kc2*32+(l>>4)*8+j][n = 16t+(l&15)]
// biasP[o]: permuted bias
__global__ void k_wcat(const void* __restrict__ Wx, const void* __restrict__ theta,
                       const void* __restrict__ bg, const void* __restrict__ convb,
                       const void* __restrict__ Wl,
                       ushort* __restrict__ Wf, float* __restrict__ biasP,
                       ushort* __restrict__ WlF, const int* __restrict__ flagp) {
    const int f32 = flagp[0];
    int gid = blockIdx.x * 256 + threadIdx.x;   // 336 blocks * 256 = 86016
    if (gid < 81920) {
        int j = gid & 7, l = (gid >> 3) & 63, tile = gid >> 9;
        int kc = tile >> 4, t = tile & 15;
        int r = kc * 32 + ((l >> 4) * 8) + j;
        int g = t & 3;
        int cc = (t >> 2) * 16 + (l & 15);
        float v;
        if (r < 128) {
            v = ldin(Wx, (g * 128 + r) * 64 + cc, f32);
        } else {
            int k3 = (r - 128) >> 6, rr = (r - 128) & 63;
            v = ldin(theta, ((g * 3 + k3) * 64 + rr) * 64 + cc, f32);
        }
        Wf[gid] = f2bu(v);
        if (gid < 256) {
            int o = gid;
            int gg = (o >> 4) & 3;
            int cc2 = (o >> 6) * 16 + (o & 15);
            biasP[o] = ldin(bg, gg * 64 + cc2, f32) + ldin(convb, gg * 64 + cc2, f32);
        }
    } else {
        int gid2 = gid - 81920;                  // [0, 4096)
        int j = gid2 & 7, l = (gid2 >> 3) & 63, tile2 = gid2 >> 9;
        int kc2 = tile2 >> 2, t = tile2 & 3;
        int k = kc2 * 32 + ((l >> 4) * 8) + j;
        int n = t * 16 + (l & 15);
        WlF[gid2] = f2bu(ldin(Wl, k * 64 + n, f32));
    }
}

// ---------------- MFMA gate GEMM [64 nodes x 256 cols] + LSTM + out ----
// F rows: 0-127 x | 128-191 h | 192-255 Tx1 | 256-319 (2*agg2 - h)
// Aliasing: Tx1 (bf16, 256B/node footprint) lives in the `out` fp32 region
// with EXACTLY matching per-node byte ranges; agg2 in `c0` region. Blocks
// only touch their own 64-node slab; reads precede writes in-block. Safe.
__global__ __launch_bounds__(256)
void k_gates(const void* __restrict__ x, const void* __restrict__ h,
             const void* __restrict__ cin,
             const ushort* __restrict__ Tx1, const float* __restrict__ agg2,
             const ushort* __restrict__ Wf, const float* __restrict__ biasP,
             const ushort* __restrict__ WlF, const void* __restrict__ bl,
             float* __restrict__ outF, float* __restrict__ h0o,
             float* __restrict__ c0o, const int* __restrict__ flagp) {
    const int f32 = flagp[0];
    __shared__ ushort As[4 * 64 * 8];    // 4 KB, A fragments for one 64x32 chunk
    __shared__ ushort Hs[64 * 72];       // 9.2 KB, relu(h0) bf16, padded stride 72
    const int tid = threadIdx.x;
    const int lane = tid & 63;
    const int w = tid >> 6;              // wave 0..3
    const int base = blockIdx.x * 64;
    // staging role: thread -> (node sm, k-quad skq)
    const int sm = tid & 63;
    const int skq = tid >> 6;
    const int snode = base + sm;
    const bool svalid = snode < NN;
    uint4* sdst = (uint4*)&As[(((sm >> 4) * 64) + ((sm & 15) + 16 * skq)) * 8];

    floatx4 acc[4][4];                   // [m-tile][gate]
    {
        float bv0 = biasP[w * 64 + 0 * 16 + (lane & 15)];
        float bv1 = biasP[w * 64 + 1 * 16 + (lane & 15)];
        float bv2 = biasP[w * 64 + 2 * 16 + (lane & 15)];
        float bv3 = biasP[w * 64 + 3 * 16 + (lane & 15)];
#pragma unroll
        for (int mt = 0; mt < 4; mt++) {
            acc[mt][0] = (floatx4){bv0, bv0, bv0, bv0};
            acc[mt][1] = (floatx4){bv1, bv1, bv1, bv1};
            acc[mt][2] = (floatx4){bv2, bv2, bv2, bv2};
            acc[mt][3] = (floatx4){bv3, bv3, bv3, bv3};
        }
    }

    for (int kc = 0; kc < 10; kc++) {
        // ---- produce this thread's 8 bf16 F-values (global loads) ----
        uint4 raw = {0, 0, 0, 0};
        if (svalid) {
            if (kc < 4) {
                raw = ld8_bf16(x, snode * 128 + kc * 32 + skq * 8, f32);
            } else if (kc < 6) {
                raw = ld8_bf16(h, snode * 64 + (kc - 4) * 32 + skq * 8, f32);
            } else if (kc < 8) {
                raw = *(const uint4*)&Tx1[(size_t)snode * 128 + (kc - 6) * 32 + skq * 8];
            } else {
                int off = snode * 64 + (kc - 8) * 32 + skq * 8;
                const float* pa = agg2 + off;
                float4 a = *(const float4*)pa, b = *(const float4*)(pa + 4);
                float av[8] = {a.x, a.y, a.z, a.w, b.x, b.y, b.z, b.w};
                float hv[8];
                if (f32) {
                    const float* ph = (const float*)h + off;
                    float4 h0_ = *(const float4*)ph, h1_ = *(const float4*)(ph + 4);
                    hv[0]=h0_.x; hv[1]=h0_.y; hv[2]=h0_.z; hv[3]=h0_.w;
                    hv[4]=h1_.x; hv[5]=h1_.y; hv[6]=h1_.z; hv[7]=h1_.w;
                } else {
                    uint4 hr = *(const uint4*)((const ushort*)h + off);
                    uint u[4] = {hr.x, hr.y, hr.z, hr.w};
#pragma unroll
                    for (int q = 0; q < 4; q++) {
                        hv[2*q]   = b2f_raw((ushort)(u[q] & 0xffff));
                        hv[2*q+1] = b2f_raw((ushort)(u[q] >> 16));
                    }
                }
                float f[8];
#pragma unroll
                for (int j = 0; j < 8; j++) f[j] = 2.f * av[j] - hv[j];
                raw = packf8(f);
            }
        }
        // ---- B fragments for this chunk (global, L2-resident) ----
        short8 bF[4];
#pragma unroll
        for (int g = 0; g < 4; g++)
            bF[g] = *(const short8*)&Wf[((kc * 16 + w * 4 + g) * 64 + lane) * 8];

        __syncthreads();                 // prior chunk's reads complete
        *sdst = raw;
        __syncthreads();                 // staging visible

        short8 aF[4];
#pragma unroll
        for (int mt = 0; mt < 4; mt++)
            aF[mt] = *(const short8*)&As[(mt * 64 + lane) * 8];
#pragma unroll
        for (int mt = 0; mt < 4; mt++)
#pragma unroll
            for (int g = 0; g < 4; g++)
                acc[mt][g] = __builtin_amdgcn_mfma_f32_16x16x32_bf16(
                    aF[mt], bF[g], acc[mt][g], 0, 0, 0);
    }

    // ---- LSTM epilogue, fully in-register (perm put all 4 gates here) ----
    const int cc = w * 16 + (lane & 15);
#pragma unroll
    for (int mt = 0; mt < 4; mt++) {
        const int m0 = mt * 16 + ((lane >> 4) * 4);
#pragma unroll
        for (int r = 0; r < 4; r++) {
            int ml = m0 + r;
            int node = base + ml;
            float gi = sigmoidf(acc[mt][0][r]);
            float gf = sigmoidf(acc[mt][1][r]);
            float gt = tanh_fast(acc[mt][2][r]);
            float go = sigmoidf(acc[mt][3][r]);
            float cv = (node < NN) ? ldin(cin, node * 64 + cc, f32) : 0.f;
            float c0 = gf * cv + gi * gt;
            float h0v = go * tanh_fast(c0);
            if (node < NN) {
                c0o[node * 64 + cc] = c0;
                h0o[node * 64 + cc] = h0v;
            }
            Hs[ml * 72 + cc] = f2bu(fmaxf(h0v, 0.f));
        }
    }
    __syncthreads();

    // ---- fused out = relu(h0) @ Wl + bl (8 MFMA per wave) ----
    float blv = ldin(bl, w * 16 + (lane & 15), f32);
    floatx4 oacc[4];
#pragma unroll
    for (int mt = 0; mt < 4; mt++) oacc[mt] = (floatx4){blv, blv, blv, blv};
#pragma unroll
    for (int kc2 = 0; kc2 < 2; kc2++) {
        short8 bW = *(const short8*)&WlF[((kc2 * 4 + w) * 64 + lane) * 8];
#pragma unroll
        for (int mt = 0; mt < 4; mt++) {
            short8 aH = *(const short8*)&Hs[(mt * 16 + (lane & 15)) * 72
                                            + kc2 * 32 + (lane >> 4) * 8];
            oacc[mt] = __builtin_amdgcn_mfma_f32_16x16x32_bf16(
                aH, bW, oacc[mt], 0, 0, 0);
        }
    }
#pragma unroll
    for (int mt = 0; mt < 4; mt++) {
        const int m0 = mt * 16 + ((lane >> 4) * 4);
#pragma unroll
        for (int r = 0; r < 4; r++) {
            int node = base + m0 + r;
            if (node < NN)
                outF[node * 64 + w * 16 + (lane & 15)] = oacc[mt][r];
        }
    }
}

extern "C" void kernel_launch(void* const* d_in, const int* in_sizes, int n_in,
                              void* d_out, int out_size, void* d_ws, size_t ws_size,
                              hipStream_t stream) {
    const void* x     = d_in[0];
    const int*  ei    = (const int*)d_in[1];
    const void* ew    = d_in[2];
    const void* h     = d_in[3];
    const void* c     = d_in[4];
    const void* Wx    = d_in[5];
    const void* bg    = d_in[6];
    const void* theta = d_in[7];
    const void* convb = d_in[8];
    const void* Wl    = d_in[9];
    const void* bl    = d_in[10];
    (void)in_sizes; (void)n_in; (void)out_size; (void)ws_size;

    // ws layout (4B words) — ~1.78 MB total
    float*  ws     = (float*)d_ws;
    int*    flag   = (int*)ws;                 // 64
    float*  deg    = ws + 64;                  // 100000 (-> dinv in place)
    int*    pcnt   = (int*)(ws + 100064);      // 100000
    int*    ovfcnt = (int*)(ws + 200064);      // 1 (+pad)
    float*  biasP  = ws + 400128;              // 256
    ushort* Wf     = (ushort*)(ws + 400384);   // 81920 ushort = 40960 words
    ushort* WlF    = (ushort*)(ws + 441344);   // 4096 ushort = 2048 words

    // d_out FP32: out [0,6.4M) | h0 [6.4M,12.8M) | c0 [12.8M,19.2M)  (words)
    float* outF = (float*)d_out;
    float* h0o  = outF + (size_t)NN * 64;
    float* c0o  = outF + (size_t)2 * NN * 64;
    // Tx1 bf16 aliases the out region with matching 256B/node footprint:
    // node n occupies ushort elems [n*128, n*128+64) = bytes [n*256, n*256+128).
    ushort* Tx1b = (ushort*)outF;
    float*  agg2 = c0o;          // alias (same-row fp32 mapping)
    // CSR (fixed cap) + overflow live in the h0 region (6.4M words):
    //   csr0 = 100000*31 int2 = 6.2M words; overflow lists in the last 200K.
    int2* csr0 = (int2*)h0o;
    int*  ovfD = (int*)h0o + 6200000;   // 66000
    int*  ovfS = ovfD + 66000;
    int*  ovfW = ovfS + 66000;

    k_sniff<<<1, 256, 0, stream>>>(x, flag);
    hipMemsetAsync(deg, 0, (size_t)200080 * 4, stream);  // deg + pcnt + ovfcnt

    k_fill3<<<(NE / 4 + 255) / 256, 256, 0, stream>>>(ei, ew, deg, pcnt, csr0,
                                                      ovfcnt, ovfD, ovfS, ovfW, flag);
    k_dinv<<<(NN + 255) / 256, 256, 0, stream>>>(deg);
    k_wcat<<<336, 256, 0, stream>>>(Wx, theta, bg, convb, Wl, Wf, biasP, WlF, flag);

    k_gath<0><<<25000, 256, 0, stream>>>(pcnt, deg, csr0, h, Tx1b,
                                         ovfcnt, ovfD, ovfS, ovfW, flag);
    k_gath<1><<<25000, 256, 0, stream>>>(pcnt, deg, csr0, Tx1b, agg2,
                                         ovfcnt, ovfD, ovfS, ovfW, flag);

    k_gates<<<(NN + 63) / 64, 256, 0, stream>>>(x, h, c, Tx1b, agg2,
                                                Wf, biasP, WlF, bl,
                                                outF, h0o, c0o, flag);
}

// Round 4
// 482.407 us; speedup vs baseline: 1.8855x; 1.2027x over previous
//
#include <hip/hip_runtime.h>
#include <hip/hip_bf16.h>

#define NN 100000
#define NE 1600000
#define INDIM 128
#define HID 64
#define BSH 9                      // 512 nodes per bucket
#define NBUCK 196                  // ceil(NN / 512)

typedef __hip_bfloat16 bf16;
typedef unsigned short ushort;
typedef unsigned int uint;
typedef __attribute__((ext_vector_type(8))) short short8;
typedef __attribute__((ext_vector_type(4))) float floatx4;

__device__ __forceinline__ float b2f(bf16 v) { return __bfloat162float(v); }
__device__ __forceinline__ float b2f_raw(ushort u) { return __uint_as_float(((uint)u) << 16); }
__device__ __forceinline__ ushort f2bu(float v) {
    bf16 t = __float2bfloat16(v);
    return *reinterpret_cast<ushort*>(&t);
}
// flag-aware input load: f32==1 -> fp32 tensor, else bf16 tensor
__device__ __forceinline__ float ldin(const void* p, int i, int f32) {
    return f32 ? ((const float*)p)[i] : b2f(((const bf16*)p)[i]);
}
__device__ __forceinline__ float sigmoidf(float x) { return 1.f / (1.f + __expf(-x)); }
__device__ __forceinline__ float tanh_fast(float x) {
    float e = __expf(2.f * x);
    return 1.f - 2.f / (e + 1.f);
}
__device__ __forceinline__ uint4 packf8(const float* f) {
    uint4 u;
    u.x = f2bu(f[0]) | ((uint)f2bu(f[1]) << 16);
    u.y = f2bu(f[2]) | ((uint)f2bu(f[3]) << 16);
    u.z = f2bu(f[4]) | ((uint)f2bu(f[5]) << 16);
    u.w = f2bu(f[6]) | ((uint)f2bu(f[7]) << 16);
    return u;
}
// 8 consecutive elements of a (bf16|fp32) tensor as packed bf16
__device__ __forceinline__ uint4 ld8_bf16(const void* p, int off, int f32) {
    if (!f32) return *(const uint4*)((const ushort*)p + off);
    const float* q = (const float*)p + off;
    float4 a = *(const float4*)q, b = *(const float4*)(q + 4);
    float f[8] = {a.x, a.y, a.z, a.w, b.x, b.y, b.z, b.w};
    return packf8(f);
}
// 4 consecutive edge weights
__device__ __forceinline__ void ld4w(const void* ew, int e0, int f32, float* w) {
    if (f32) {
        float4 v = *(const float4*)((const float*)ew + e0);
        w[0] = v.x; w[1] = v.y; w[2] = v.z; w[3] = v.w;
    } else {
        uint2 v = *(const uint2*)((const ushort*)ew + e0);
        w[0] = b2f_raw((ushort)(v.x & 0xffff)); w[1] = b2f_raw((ushort)(v.x >> 16));
        w[2] = b2f_raw((ushort)(v.y & 0xffff)); w[3] = b2f_raw((ushort)(v.y >> 16));
    }
}

// ---------------- dtype sniffer ----------------------------------------
__global__ void k_sniff(const void* __restrict__ x, int* __restrict__ flag) {
    __shared__ int cnt;
    if (threadIdx.x == 0) cnt = 0;
    __syncthreads();
    const bf16* p = (const bf16*)x;
    int bad = 0;
    for (int i = threadIdx.x; i < 8192; i += 256) {
        float v = b2f(p[i]);
        if (!(fabsf(v) < 1e6f)) bad++;
    }
    atomicAdd(&cnt, bad);
    __syncthreads();
    if (threadIdx.x == 0) flag[0] = (cnt > 32) ? 1 : 0;
}

// ---------------- pass 1: per-bucket counts (dst bins + src bins) ------
__global__ __launch_bounds__(256)
void k_count(const int* __restrict__ ei, int* __restrict__ gcntD,
             int* __restrict__ gcntS) {
    __shared__ int hD[NBUCK], hS[NBUCK];
    for (int i = threadIdx.x; i < NBUCK; i += 256) { hD[i] = 0; hS[i] = 0; }
    __syncthreads();
    int e0 = (blockIdx.x * 256 + threadIdx.x) * 16;
    if (e0 < NE) {
        if (e0 + 16 <= NE) {
#pragma unroll
            for (int q = 0; q < 4; q++) {
                int4 s4 = *(const int4*)(ei + e0 + q * 4);
                int4 d4 = *(const int4*)(ei + NE + e0 + q * 4);
                int ss[4] = {s4.x, s4.y, s4.z, s4.w};
                int dd[4] = {d4.x, d4.y, d4.z, d4.w};
#pragma unroll
                for (int j = 0; j < 4; j++)
                    if (ss[j] != dd[j]) {
                        atomicAdd(hD + (dd[j] >> BSH), 1);
                        atomicAdd(hS + (ss[j] >> BSH), 1);
                    }
            }
        } else {
            for (int e = e0; e < NE; e++) {
                int s = ei[e], d = ei[NE + e];
                if (s != d) {
                    atomicAdd(hD + (d >> BSH), 1);
                    atomicAdd(hS + (s >> BSH), 1);
                }
            }
        }
    }
    __syncthreads();
    for (int i = threadIdx.x; i < NBUCK; i += 256) {
        if (hD[i]) atomicAdd(gcntD + i, hD[i]);
        if (hS[i]) atomicAdd(gcntS + i, hS[i]);
    }
}

// ---------------- pass 2: scan bucket counts -> bases + cursors --------
__global__ __launch_bounds__(256)
void k_scanb(const int* __restrict__ gcntD, const int* __restrict__ gcntS,
             int* __restrict__ bbaseD, int* __restrict__ bbaseS,
             int* __restrict__ gcurD, int* __restrict__ gcurS,
             int* __restrict__ rowptr) {
    __shared__ int sh[256];
    const int t = threadIdx.x;
    int v = (t < NBUCK) ? gcntD[t] : 0;
    sh[t] = v; __syncthreads();
    for (int off = 1; off < 256; off <<= 1) {
        int u = (t >= off) ? sh[t - off] : 0;
        __syncthreads(); sh[t] += u; __syncthreads();
    }
    if (t < NBUCK) { int e = sh[t] - v; bbaseD[t] = e; gcurD[t] = e; }
    if (t == 255) { bbaseD[NBUCK] = sh[255]; rowptr[NN] = sh[255]; }
    __syncthreads();
    int v2 = (t < NBUCK) ? gcntS[t] : 0;
    sh[t] = v2; __syncthreads();
    for (int off = 1; off < 256; off <<= 1) {
        int u = (t >= off) ? sh[t - off] : 0;
        __syncthreads(); sh[t] += u; __syncthreads();
    }
    if (t < NBUCK) { int e = sh[t] - v2; bbaseS[t] = e; gcurS[t] = e; }
    if (t == 255) bbaseS[NBUCK] = sh[255];
}

// ---------------- pass 3: partition edges into bucketed record streams -
// recD = {src | dlocal<<17, w}  binned by dst>>BSH
// recS = {slocal, w}            binned by src>>BSH
__global__ __launch_bounds__(256)
void k_part(const int* __restrict__ ei, const void* __restrict__ ew,
            int* __restrict__ gcurD, int* __restrict__ gcurS,
            int2* __restrict__ recD, int2* __restrict__ recS,
            const int* __restrict__ flagp) {
    const int f32 = flagp[0];
    __shared__ int cD[NBUCK], cS[NBUCK], bD[NBUCK], bS[NBUCK];
    for (int i = threadIdx.x; i < NBUCK; i += 256) { cD[i] = 0; cS[i] = 0; }
    __syncthreads();
    const int e0 = (blockIdx.x * 256 + threadIdx.x) * 8;
    int s[8], d[8], rD[8], rS[8];
    float w[8];
    bool act[8];
    if (e0 + 8 <= NE) {
        int4 sa = *(const int4*)(ei + e0), sb = *(const int4*)(ei + e0 + 4);
        int4 da = *(const int4*)(ei + NE + e0), db = *(const int4*)(ei + NE + e0 + 4);
        s[0]=sa.x; s[1]=sa.y; s[2]=sa.z; s[3]=sa.w;
        s[4]=sb.x; s[5]=sb.y; s[6]=sb.z; s[7]=sb.w;
        d[0]=da.x; d[1]=da.y; d[2]=da.z; d[3]=da.w;
        d[4]=db.x; d[5]=db.y; d[6]=db.z; d[7]=db.w;
        ld4w(ew, e0, f32, w); ld4w(ew, e0 + 4, f32, w + 4);
#pragma unroll
        for (int j = 0; j < 8; j++) act[j] = (s[j] != d[j]);
    } else {
#pragma unroll
        for (int j = 0; j < 8; j++) {
            int e = e0 + j;
            if (e < NE) {
                s[j] = ei[e]; d[j] = ei[NE + e]; w[j] = ldin(ew, e, f32);
                act[j] = (s[j] != d[j]);
            } else { s[j] = 0; d[j] = 0; w[j] = 0.f; act[j] = false; }
        }
    }
#pragma unroll
    for (int j = 0; j < 8; j++)
        if (act[j]) {
            rD[j] = atomicAdd(cD + (d[j] >> BSH), 1);
            rS[j] = atomicAdd(cS + (s[j] >> BSH), 1);
        }
    __syncthreads();
    for (int i = threadIdx.x; i < NBUCK; i += 256) {
        bD[i] = cD[i] ? atomicAdd(gcurD + i, cD[i]) : 0;
        bS[i] = cS[i] ? atomicAdd(gcurS + i, cS[i]) : 0;
    }
    __syncthreads();
#pragma unroll
    for (int j = 0; j < 8; j++)
        if (act[j]) {
            int2 pd; pd.x = s[j] | ((d[j] & 511) << 17); pd.y = __float_as_int(w[j]);
            recD[bD[d[j] >> BSH] + rD[j]] = pd;
            int2 ps; ps.x = s[j] & 511; ps.y = __float_as_int(w[j]);
            recS[bS[s[j] >> BSH] + rS[j]] = ps;
        }
}

// ---------------- pass 4: per-bucket build (all node-indexed work in LDS)
// compact CSR + rowptr + dinv, coalesced global writes.
__global__ __launch_bounds__(512)
void k_build(const int2* __restrict__ recD, const int2* __restrict__ recS,
             const int* __restrict__ bbaseD, const int* __restrict__ bbaseS,
             int* __restrict__ rowptr, int2* __restrict__ csr,
             float* __restrict__ dinv) {
    __shared__ int cnt[512], sh[512], cur[512];
    __shared__ float degf[512];
    const int t = threadIdx.x, b = blockIdx.x;
    cnt[t] = 0; degf[t] = 0.f;
    __syncthreads();
    const int dbase = bbaseD[b], dend = bbaseD[b + 1];
    const int sbase = bbaseS[b], send = bbaseS[b + 1];
    const int nD = dend - dbase, nS = send - sbase;
    const int2* rd = recD + dbase;
    const int2* rs = recS + sbase;
    for (int i = t; i < nD; i += 512) atomicAdd(cnt + (rd[i].x >> 17), 1);
    for (int i = t; i < nS; i += 512) atomicAdd(degf + rs[i].x, __int_as_float(rs[i].y));
    __syncthreads();
    const int own = cnt[t];
    sh[t] = own; __syncthreads();
    for (int off = 1; off < 512; off <<= 1) {
        int u = (t >= off) ? sh[t - off] : 0;
        __syncthreads(); sh[t] += u; __syncthreads();
    }
    const int rstart = dbase + sh[t] - own;
    cur[t] = rstart;
    const int node = (b << BSH) + t;
    if (node < NN) {
        rowptr[node] = rstart;
        float dg = degf[t];
        dinv[node] = dg > 0.f ? rsqrtf(dg) : 0.f;
    }
    __syncthreads();
    for (int i = t; i < nD; i += 512) {
        int2 r = rd[i];
        int pos = atomicAdd(cur + (r.x >> 17), 1);
        int2 o; o.x = r.x & 0x1FFFF; o.y = r.y;
        csr[pos] = o;
    }
}

// ---------------- gather SpMM: one wave per dst, register accumulate ---
// out[dst] = -dinv[dst] * sum_e dinv[src_e] * w_e * z[src_e]
// MODE 0: z = h (flag dtype, stride 64)  -> out bf16, row stride 128 elems
// MODE 1: z = bf16 stride-128 rows       -> out fp32, stride 64
template<int MODE>
__global__ __launch_bounds__(256)
void k_gath(const int* __restrict__ rowptr, const float* __restrict__ dinv,
            const int2* __restrict__ csr, const void* __restrict__ zin,
            void* __restrict__ outv, const int* __restrict__ flagp) {
    const int f32 = flagp[0];
    int n = (blockIdx.x * 256 + threadIdx.x) >> 6;   // dst node
    int lane = threadIdx.x & 63;
    if (n >= NN) return;
    int b0 = rowptr[n], e0 = rowptr[n + 1];
    const int2* row = csr + b0;
    int cnt = e0 - b0;
    float acc = 0.f;
    int i = 0;
#define ZLD(sidx) (MODE == 0 ? ldin(zin, (sidx) * 64 + lane, f32) \
                             : b2f_raw(((const ushort*)zin)[(sidx) * 128 + lane]))
    for (; i + 3 < cnt; i += 4) {
        int2 p0 = row[i], p1 = row[i + 1], p2 = row[i + 2], p3 = row[i + 3];
        float z0 = ZLD(p0.x), z1 = ZLD(p1.x), z2 = ZLD(p2.x), z3 = ZLD(p3.x);
        acc = fmaf(dinv[p0.x] * __int_as_float(p0.y), z0, acc);
        acc = fmaf(dinv[p1.x] * __int_as_float(p1.y), z1, acc);
        acc = fmaf(dinv[p2.x] * __int_as_float(p2.y), z2, acc);
        acc = fmaf(dinv[p3.x] * __int_as_float(p3.y), z3, acc);
    }
    for (; i < cnt; i++) {
        int2 p0 = row[i];
        float z0 = ZLD(p0.x);
        acc = fmaf(dinv[p0.x] * __int_as_float(p0.y), z0, acc);
    }
#undef ZLD
    float r = -dinv[n] * acc;
    if (MODE == 0) ((ushort*)outv)[(size_t)n * 128 + lane] = f2bu(r);
    else           ((float*)outv)[(size_t)n * 64 + lane] = r;
}

// ---------------- pre-swizzle weights into MFMA fragment order ---------
// Wf: [kc 0..9][t 0..15][lane 0..63][j 0..7] bf16, element =
//     W[r = kc*32 + (lane>>4)*8 + j][o = 16t + (lane&15)] with column perm
//     o = 16t+(l&15): gate g = t&3, cc = (t>>2)*16 + (lane&15)
// WlF: [kc2 0..1][t 0..3][lane][j], Wl[k = kc2*32+(l>>4)*8+j][n = 16t+(l&15)]
// biasP[o]: permuted bias
__global__ void k_wcat(const void* __restrict__ Wx, const void* __restrict__ theta,
                       const void* __restrict__ bg, const void* __restrict__ convb,
                       const void* __restrict__ Wl,
                       ushort* __restrict__ Wf, float* __restrict__ biasP,
                       ushort* __restrict__ WlF, const int* __restrict__ flagp) {
    const int f32 = flagp[0];
    int gid = blockIdx.x * 256 + threadIdx.x;   // 336 blocks * 256 = 86016
    if (gid < 81920) {
        int j = gid & 7, l = (gid >> 3) & 63, tile = gid >> 9;
        int kc = tile >> 4, t = tile & 15;
        int r = kc * 32 + ((l >> 4) * 8) + j;
        int g = t & 3;
        int cc = (t >> 2) * 16 + (l & 15);
        float v;
        if (r < 128) {
            v = ldin(Wx, (g * 128 + r) * 64 + cc, f32);
        } else {
            int k3 = (r - 128) >> 6, rr = (r - 128) & 63;
            v = ldin(theta, ((g * 3 + k3) * 64 + rr) * 64 + cc, f32);
        }
        Wf[gid] = f2bu(v);
        if (gid < 256) {
            int o = gid;
            int gg = (o >> 4) & 3;
            int cc2 = (o >> 6) * 16 + (o & 15);
            biasP[o] = ldin(bg, gg * 64 + cc2, f32) + ldin(convb, gg * 64 + cc2, f32);
        }
    } else {
        int gid2 = gid - 81920;                  // [0, 4096)
        int j = gid2 & 7, l = (gid2 >> 3) & 63, tile2 = gid2 >> 9;
        int kc2 = tile2 >> 2, t = tile2 & 3;
        int k = kc2 * 32 + ((l >> 4) * 8) + j;
        int n = t * 16 + (l & 15);
        WlF[gid2] = f2bu(ldin(Wl, k * 64 + n, f32));
    }
}

// ---------------- MFMA gate GEMM [64 nodes x 256 cols] + LSTM + out ----
// F rows: 0-127 x | 128-191 h | 192-255 Tx1 | 256-319 (2*agg2 - h)
// Aliasing: Tx1 (bf16, 256B/node footprint) lives in the `out` fp32 region
// with EXACTLY matching per-node byte ranges; agg2 in `c0` region. Blocks
// only touch their own 64-node slab; reads precede writes in-block. Safe.
__global__ __launch_bounds__(256)
void k_gates(const void* __restrict__ x, const void* __restrict__ h,
             const void* __restrict__ cin,
             const ushort* __restrict__ Tx1, const float* __restrict__ agg2,
             const ushort* __restrict__ Wf, const float* __restrict__ biasP,
             const ushort* __restrict__ WlF, const void* __restrict__ bl,
             float* __restrict__ outF, float* __restrict__ h0o,
             float* __restrict__ c0o, const int* __restrict__ flagp) {
    const int f32 = flagp[0];
    __shared__ ushort As[4 * 64 * 8];    // 4 KB, A fragments for one 64x32 chunk
    __shared__ ushort Hs[64 * 72];       // 9.2 KB, relu(h0) bf16, padded stride 72
    const int tid = threadIdx.x;
    const int lane = tid & 63;
    const int w = tid >> 6;              // wave 0..3
    const int base = blockIdx.x * 64;
    // staging role: thread -> (node sm, k-quad skq)
    const int sm = tid & 63;
    const int skq = tid >> 6;
    const int snode = base + sm;
    const bool svalid = snode < NN;
    uint4* sdst = (uint4*)&As[(((sm >> 4) * 64) + ((sm & 15) + 16 * skq)) * 8];

    floatx4 acc[4][4];                   // [m-tile][gate]
    {
        float bv0 = biasP[w * 64 + 0 * 16 + (lane & 15)];
        float bv1 = biasP[w * 64 + 1 * 16 + (lane & 15)];
        float bv2 = biasP[w * 64 + 2 * 16 + (lane & 15)];
        float bv3 = biasP[w * 64 + 3 * 16 + (lane & 15)];
#pragma unroll
        for (int mt = 0; mt < 4; mt++) {
            acc[mt][0] = (floatx4){bv0, bv0, bv0, bv0};
            acc[mt][1] = (floatx4){bv1, bv1, bv1, bv1};
            acc[mt][2] = (floatx4){bv2, bv2, bv2, bv2};
            acc[mt][3] = (floatx4){bv3, bv3, bv3, bv3};
        }
    }

    for (int kc = 0; kc < 10; kc++) {
        // ---- produce this thread's 8 bf16 F-values (global loads) ----
        uint4 raw = {0, 0, 0, 0};
        if (svalid) {
            if (kc < 4) {
                raw = ld8_bf16(x, snode * 128 + kc * 32 + skq * 8, f32);
            } else if (kc < 6) {
                raw = ld8_bf16(h, snode * 64 + (kc - 4) * 32 + skq * 8, f32);
            } else if (kc < 8) {
                raw = *(const uint4*)&Tx1[(size_t)snode * 128 + (kc - 6) * 32 + skq * 8];
            } else {
                int off = snode * 64 + (kc - 8) * 32 + skq * 8;
                const float* pa = agg2 + off;
                float4 a = *(const float4*)pa, b = *(const float4*)(pa + 4);
                float av[8] = {a.x, a.y, a.z, a.w, b.x, b.y, b.z, b.w};
                float hv[8];
                if (f32) {
                    const float* ph = (const float*)h + off;
                    float4 h0_ = *(const float4*)ph, h1_ = *(const float4*)(ph + 4);
                    hv[0]=h0_.x; hv[1]=h0_.y; hv[2]=h0_.z; hv[3]=h0_.w;
                    hv[4]=h1_.x; hv[5]=h1_.y; hv[6]=h1_.z; hv[7]=h1_.w;
                } else {
                    uint4 hr = *(const uint4*)((const ushort*)h + off);
                    uint u[4] = {hr.x, hr.y, hr.z, hr.w};
#pragma unroll
                    for (int q = 0; q < 4; q++) {
                        hv[2*q]   = b2f_raw((ushort)(u[q] & 0xffff));
                        hv[2*q+1] = b2f_raw((ushort)(u[q] >> 16));
                    }
                }
                float f[8];
#pragma unroll
                for (int j = 0; j < 8; j++) f[j] = 2.f * av[j] - hv[j];
                raw = packf8(f);
            }
        }
        // ---- B fragments for this chunk (global, L2-resident) ----
        short8 bF[4];
#pragma unroll
        for (int g = 0; g < 4; g++)
            bF[g] = *(const short8*)&Wf[((kc * 16 + w * 4 + g) * 64 + lane) * 8];

        __syncthreads();                 // prior chunk's reads complete
        *sdst = raw;
        __syncthreads();                 // staging visible

        short8 aF[4];
#pragma unroll
        for (int mt = 0; mt < 4; mt++)
            aF[mt] = *(const short8*)&As[(mt * 64 + lane) * 8];
#pragma unroll
        for (int mt = 0; mt < 4; mt++)
#pragma unroll
            for (int g = 0; g < 4; g++)
                acc[mt][g] = __builtin_amdgcn_mfma_f32_16x16x32_bf16(
                    aF[mt], bF[g], acc[mt][g], 0, 0, 0);
    }

    // ---- LSTM epilogue, fully in-register (perm put all 4 gates here) ----
    const int cc = w * 16 + (lane & 15);
#pragma unroll
    for (int mt = 0; mt < 4; mt++) {
        const int m0 = mt * 16 + ((lane >> 4) * 4);
#pragma unroll
        for (int r = 0; r < 4; r++) {
            int ml = m0 + r;
            int node = base + ml;
            float gi = sigmoidf(acc[mt][0][r]);
            float gf = sigmoidf(acc[mt][1][r]);
            float gt = tanh_fast(acc[mt][2][r]);
            float go = sigmoidf(acc[mt][3][r]);
            float cv = (node < NN) ? ldin(cin, node * 64 + cc, f32) : 0.f;
            float c0 = gf * cv + gi * gt;
            float h0v = go * tanh_fast(c0);
            if (node < NN) {
                c0o[node * 64 + cc] = c0;
                h0o[node * 64 + cc] = h0v;
            }
            Hs[ml * 72 + cc] = f2bu(fmaxf(h0v, 0.f));
        }
    }
    __syncthreads();

    // ---- fused out = relu(h0) @ Wl + bl (8 MFMA per wave) ----
    float blv = ldin(bl, w * 16 + (lane & 15), f32);
    floatx4 oacc[4];
#pragma unroll
    for (int mt = 0; mt < 4; mt++) oacc[mt] = (floatx4){blv, blv, blv, blv};
#pragma unroll
    for (int kc2 = 0; kc2 < 2; kc2++) {
        short8 bW = *(const short8*)&WlF[((kc2 * 4 + w) * 64 + lane) * 8];
#pragma unroll
        for (int mt = 0; mt < 4; mt++) {
            short8 aH = *(const short8*)&Hs[(mt * 16 + (lane & 15)) * 72
                                            + kc2 * 32 + (lane >> 4) * 8];
            oacc[mt] = __builtin_amdgcn_mfma_f32_16x16x32_bf16(
                aH, bW, oacc[mt], 0, 0, 0);
        }
    }
#pragma unroll
    for (int mt = 0; mt < 4; mt++) {
        const int m0 = mt * 16 + ((lane >> 4) * 4);
#pragma unroll
        for (int r = 0; r < 4; r++) {
            int node = base + m0 + r;
            if (node < NN)
                outF[node * 64 + w * 16 + (lane & 15)] = oacc[mt][r];
        }
    }
}

extern "C" void kernel_launch(void* const* d_in, const int* in_sizes, int n_in,
                              void* d_out, int out_size, void* d_ws, size_t ws_size,
                              hipStream_t stream) {
    const void* x     = d_in[0];
    const int*  ei    = (const int*)d_in[1];
    const void* ew    = d_in[2];
    const void* h     = d_in[3];
    const void* c     = d_in[4];
    const void* Wx    = d_in[5];
    const void* bg    = d_in[6];
    const void* theta = d_in[7];
    const void* convb = d_in[8];
    const void* Wl    = d_in[9];
    const void* bl    = d_in[10];
    (void)in_sizes; (void)n_in; (void)out_size; (void)ws_size;

    // ws layout (4B words) — ~1.78 MB total
    float*  ws     = (float*)d_ws;
    int*    flag   = (int*)ws;                 // 64
    float*  dinv   = ws + 64;                  // 100000
    int*    rowptr = (int*)(ws + 100064);      // 100001 (pad to 100064)
    int*    gcntD  = (int*)(ws + 200128);      // 256
    int*    gcntS  = (int*)(ws + 200384);      // 256
    int*    bbaseD = (int*)(ws + 200640);      // 197 (pad 256)
    int*    bbaseS = (int*)(ws + 200896);      // 197
    int*    gcurD  = (int*)(ws + 201152);      // 256
    int*    gcurS  = (int*)(ws + 201408);      // 256
    float*  biasP  = ws + 400128;              // 256
    ushort* Wf     = (ushort*)(ws + 400384);   // 81920 ushort = 40960 words
    ushort* WlF    = (ushort*)(ws + 441344);   // 4096 ushort = 2048 words

    // d_out FP32: out [0,6.4M) | h0 [6.4M,12.8M) | c0 [12.8M,19.2M)  (words)
    float* outF = (float*)d_out;
    float* h0o  = outF + (size_t)NN * 64;
    float* c0o  = outF + (size_t)2 * NN * 64;
    // Tx1 bf16 aliases the out region with matching 256B/node footprint.
    ushort* Tx1b = (ushort*)outF;
    float*  agg2 = c0o;                  // alias (same-row fp32 mapping)
    // h0 region (6.4M words): recD [0,3.2M) + csr [3.2M,6.4M)
    //   recD written by k_part, read by k_build; csr written by k_build,
    //   read by gaths; whole region overwritten by k_gates h0 at the end.
    int2* recD = (int2*)h0o;
    int2* csr  = (int2*)(h0o + 3200000);
    // c0 region: recS [0,3.2M) — dead after k_build, then agg2 overwrites.
    int2* recS = (int2*)c0o;

    k_sniff<<<1, 256, 0, stream>>>(x, flag);
    hipMemsetAsync(gcntD, 0, 512 * 4, stream);   // gcntD + gcntS

    k_count<<<(NE + 4095) / 4096, 256, 0, stream>>>(ei, gcntD, gcntS);
    k_scanb<<<1, 256, 0, stream>>>(gcntD, gcntS, bbaseD, bbaseS, gcurD, gcurS, rowptr);
    k_part<<<(NE + 2047) / 2048, 256, 0, stream>>>(ei, ew, gcurD, gcurS,
                                                   recD, recS, flag);
    k_build<<<NBUCK, 512, 0, stream>>>(recD, recS, bbaseD, bbaseS,
                                       rowptr, csr, dinv);
    k_wcat<<<336, 256, 0, stream>>>(Wx, theta, bg, convb, Wl, Wf, biasP, WlF, flag);

    k_gath<0><<<25000, 256, 0, stream>>>(rowptr, dinv, csr, h,    Tx1b, flag);
    k_gath<1><<<25000, 256, 0, stream>>>(rowptr, dinv, csr, Tx1b, agg2, flag);

    k_gates<<<(NN + 63) / 64, 256, 0, stream>>>(x, h, c, Tx1b, agg2,
                                                Wf, biasP, WlF, bl,
                                                outF, h0o, c0o, flag);
}

// Round 5
// 478.519 us; speedup vs baseline: 1.9009x; 1.0081x over previous
//
#include <hip/hip_runtime.h>
#include <hip/hip_bf16.h>

#define NN 100000
#define NE 1600000
#define INDIM 128
#define HID 64
#define BSH 9                      // 512 nodes per bucket
#define NBUCK 196                  // ceil(NN / 512)

typedef __hip_bfloat16 bf16;
typedef unsigned short ushort;
typedef unsigned int uint;
typedef __attribute__((ext_vector_type(8))) short short8;
typedef __attribute__((ext_vector_type(4))) float floatx4;

__device__ __forceinline__ float b2f(bf16 v) { return __bfloat162float(v); }
__device__ __forceinline__ float b2f_raw(ushort u) { return __uint_as_float(((uint)u) << 16); }
__device__ __forceinline__ ushort f2bu(float v) {
    bf16 t = __float2bfloat16(v);
    return *reinterpret_cast<ushort*>(&t);
}
// flag-aware input load: f32==1 -> fp32 tensor, else bf16 tensor
__device__ __forceinline__ float ldin(const void* p, int i, int f32) {
    return f32 ? ((const float*)p)[i] : b2f(((const bf16*)p)[i]);
}
__device__ __forceinline__ float sigmoidf(float x) { return 1.f / (1.f + __expf(-x)); }
__device__ __forceinline__ float tanh_fast(float x) {
    float e = __expf(2.f * x);
    return 1.f - 2.f / (e + 1.f);
}
__device__ __forceinline__ uint4 packf8(const float* f) {
    uint4 u;
    u.x = f2bu(f[0]) | ((uint)f2bu(f[1]) << 16);
    u.y = f2bu(f[2]) | ((uint)f2bu(f[3]) << 16);
    u.z = f2bu(f[4]) | ((uint)f2bu(f[5]) << 16);
    u.w = f2bu(f[6]) | ((uint)f2bu(f[7]) << 16);
    return u;
}
// 8 consecutive elements of a (bf16|fp32) tensor as packed bf16
__device__ __forceinline__ uint4 ld8_bf16(const void* p, int off, int f32) {
    if (!f32) return *(const uint4*)((const ushort*)p + off);
    const float* q = (const float*)p + off;
    float4 a = *(const float4*)q, b = *(const float4*)(q + 4);
    float f[8] = {a.x, a.y, a.z, a.w, b.x, b.y, b.z, b.w};
    return packf8(f);
}
// 4 consecutive edge weights
__device__ __forceinline__ void ld4w(const void* ew, int e0, int f32, float* w) {
    if (f32) {
        float4 v = *(const float4*)((const float*)ew + e0);
        w[0] = v.x; w[1] = v.y; w[2] = v.z; w[3] = v.w;
    } else {
        uint2 v = *(const uint2*)((const ushort*)ew + e0);
        w[0] = b2f_raw((ushort)(v.x & 0xffff)); w[1] = b2f_raw((ushort)(v.x >> 16));
        w[2] = b2f_raw((ushort)(v.y & 0xffff)); w[3] = b2f_raw((ushort)(v.y >> 16));
    }
}

// ---------------- dtype sniffer ----------------------------------------
__global__ void k_sniff(const void* __restrict__ x, int* __restrict__ flag) {
    __shared__ int cnt;
    if (threadIdx.x == 0) cnt = 0;
    __syncthreads();
    const bf16* p = (const bf16*)x;
    int bad = 0;
    for (int i = threadIdx.x; i < 8192; i += 256) {
        float v = b2f(p[i]);
        if (!(fabsf(v) < 1e6f)) bad++;
    }
    atomicAdd(&cnt, bad);
    __syncthreads();
    if (threadIdx.x == 0) flag[0] = (cnt > 32) ? 1 : 0;
}

// ---------------- pass 1: per-bucket counts (dst bins + src bins) ------
__global__ __launch_bounds__(256)
void k_count(const int* __restrict__ ei, int* __restrict__ gcntD,
             int* __restrict__ gcntS) {
    __shared__ int hD[NBUCK], hS[NBUCK];
    for (int i = threadIdx.x; i < NBUCK; i += 256) { hD[i] = 0; hS[i] = 0; }
    __syncthreads();
    int e0 = (blockIdx.x * 256 + threadIdx.x) * 16;
    if (e0 < NE) {
        if (e0 + 16 <= NE) {
#pragma unroll
            for (int q = 0; q < 4; q++) {
                int4 s4 = *(const int4*)(ei + e0 + q * 4);
                int4 d4 = *(const int4*)(ei + NE + e0 + q * 4);
                int ss[4] = {s4.x, s4.y, s4.z, s4.w};
                int dd[4] = {d4.x, d4.y, d4.z, d4.w};
#pragma unroll
                for (int j = 0; j < 4; j++)
                    if (ss[j] != dd[j]) {
                        atomicAdd(hD + (dd[j] >> BSH), 1);
                        atomicAdd(hS + (ss[j] >> BSH), 1);
                    }
            }
        } else {
            for (int e = e0; e < NE; e++) {
                int s = ei[e], d = ei[NE + e];
                if (s != d) {
                    atomicAdd(hD + (d >> BSH), 1);
                    atomicAdd(hS + (s >> BSH), 1);
                }
            }
        }
    }
    __syncthreads();
    for (int i = threadIdx.x; i < NBUCK; i += 256) {
        if (hD[i]) atomicAdd(gcntD + i, hD[i]);
        if (hS[i]) atomicAdd(gcntS + i, hS[i]);
    }
}

// ---------------- pass 2: scan bucket counts -> bases + cursors --------
__global__ __launch_bounds__(256)
void k_scanb(const int* __restrict__ gcntD, const int* __restrict__ gcntS,
             int* __restrict__ bbaseD, int* __restrict__ bbaseS,
             int* __restrict__ gcurD, int* __restrict__ gcurS,
             int* __restrict__ rowptr) {
    __shared__ int sh[256];
    const int t = threadIdx.x;
    int v = (t < NBUCK) ? gcntD[t] : 0;
    sh[t] = v; __syncthreads();
    for (int off = 1; off < 256; off <<= 1) {
        int u = (t >= off) ? sh[t - off] : 0;
        __syncthreads(); sh[t] += u; __syncthreads();
    }
    if (t < NBUCK) { int e = sh[t] - v; bbaseD[t] = e; gcurD[t] = e; }
    if (t == 255) { bbaseD[NBUCK] = sh[255]; rowptr[NN] = sh[255]; }
    __syncthreads();
    int v2 = (t < NBUCK) ? gcntS[t] : 0;
    sh[t] = v2; __syncthreads();
    for (int off = 1; off < 256; off <<= 1) {
        int u = (t >= off) ? sh[t - off] : 0;
        __syncthreads(); sh[t] += u; __syncthreads();
    }
    if (t < NBUCK) { int e = sh[t] - v2; bbaseS[t] = e; gcurS[t] = e; }
    if (t == 255) bbaseS[NBUCK] = sh[255];
}

// ---------------- pass 3: partition edges into bucketed record streams -
// recD = {src | dlocal<<17, w}  binned by dst>>BSH
// recS = {slocal, w}            binned by src>>BSH
__global__ __launch_bounds__(256)
void k_part(const int* __restrict__ ei, const void* __restrict__ ew,
            int* __restrict__ gcurD, int* __restrict__ gcurS,
            int2* __restrict__ recD, int2* __restrict__ recS,
            const int* __restrict__ flagp) {
    const int f32 = flagp[0];
    __shared__ int cD[NBUCK], cS[NBUCK], bD[NBUCK], bS[NBUCK];
    for (int i = threadIdx.x; i < NBUCK; i += 256) { cD[i] = 0; cS[i] = 0; }
    __syncthreads();
    const int e0 = (blockIdx.x * 256 + threadIdx.x) * 8;
    int s[8], d[8], rD[8], rS[8];
    float w[8];
    bool act[8];
    if (e0 + 8 <= NE) {
        int4 sa = *(const int4*)(ei + e0), sb = *(const int4*)(ei + e0 + 4);
        int4 da = *(const int4*)(ei + NE + e0), db = *(const int4*)(ei + NE + e0 + 4);
        s[0]=sa.x; s[1]=sa.y; s[2]=sa.z; s[3]=sa.w;
        s[4]=sb.x; s[5]=sb.y; s[6]=sb.z; s[7]=sb.w;
        d[0]=da.x; d[1]=da.y; d[2]=da.z; d[3]=da.w;
        d[4]=db.x; d[5]=db.y; d[6]=db.z; d[7]=db.w;
        ld4w(ew, e0, f32, w); ld4w(ew, e0 + 4, f32, w + 4);
#pragma unroll
        for (int j = 0; j < 8; j++) act[j] = (s[j] != d[j]);
    } else {
#pragma unroll
        for (int j = 0; j < 8; j++) {
            int e = e0 + j;
            if (e < NE) {
                s[j] = ei[e]; d[j] = ei[NE + e]; w[j] = ldin(ew, e, f32);
                act[j] = (s[j] != d[j]);
            } else { s[j] = 0; d[j] = 0; w[j] = 0.f; act[j] = false; }
        }
    }
#pragma unroll
    for (int j = 0; j < 8; j++)
        if (act[j]) {
            rD[j] = atomicAdd(cD + (d[j] >> BSH), 1);
            rS[j] = atomicAdd(cS + (s[j] >> BSH), 1);
        }
    __syncthreads();
    for (int i = threadIdx.x; i < NBUCK; i += 256) {
        bD[i] = cD[i] ? atomicAdd(gcurD + i, cD[i]) : 0;
        bS[i] = cS[i] ? atomicAdd(gcurS + i, cS[i]) : 0;
    }
    __syncthreads();
#pragma unroll
    for (int j = 0; j < 8; j++)
        if (act[j]) {
            int2 pd; pd.x = s[j] | ((d[j] & 511) << 17); pd.y = __float_as_int(w[j]);
            recD[bD[d[j] >> BSH] + rD[j]] = pd;
            int2 ps; ps.x = s[j] & 511; ps.y = __float_as_int(w[j]);
            recS[bS[s[j] >> BSH] + rS[j]] = ps;
        }
}

// ---------------- pass 4: per-bucket build (all node-indexed work in LDS)
// compact CSR + rowptr + dinv, coalesced global writes.
__global__ __launch_bounds__(512)
void k_build(const int2* __restrict__ recD, const int2* __restrict__ recS,
             const int* __restrict__ bbaseD, const int* __restrict__ bbaseS,
             int* __restrict__ rowptr, int2* __restrict__ csr,
             float* __restrict__ dinv) {
    __shared__ int cnt[512], sh[512], cur[512];
    __shared__ float degf[512];
    const int t = threadIdx.x, b = blockIdx.x;
    cnt[t] = 0; degf[t] = 0.f;
    __syncthreads();
    const int dbase = bbaseD[b], dend = bbaseD[b + 1];
    const int sbase = bbaseS[b], send = bbaseS[b + 1];
    const int nD = dend - dbase, nS = send - sbase;
    const int2* rd = recD + dbase;
    const int2* rs = recS + sbase;
    for (int i = t; i < nD; i += 512) atomicAdd(cnt + (rd[i].x >> 17), 1);
    for (int i = t; i < nS; i += 512) atomicAdd(degf + rs[i].x, __int_as_float(rs[i].y));
    __syncthreads();
    const int own = cnt[t];
    sh[t] = own; __syncthreads();
    for (int off = 1; off < 512; off <<= 1) {
        int u = (t >= off) ? sh[t - off] : 0;
        __syncthreads(); sh[t] += u; __syncthreads();
    }
    const int rstart = dbase + sh[t] - own;
    cur[t] = rstart;
    const int node = (b << BSH) + t;
    if (node < NN) {
        rowptr[node] = rstart;
        float dg = degf[t];
        dinv[node] = dg > 0.f ? rsqrtf(dg) : 0.f;
    }
    __syncthreads();
    for (int i = t; i < nD; i += 512) {
        int2 r = rd[i];
        int pos = atomicAdd(cur + (r.x >> 17), 1);
        int2 o; o.x = r.x & 0x1FFFF; o.y = r.y;
        csr[pos] = o;
    }
}

// ---------------- gather SpMM: one wave per dst, register accumulate ---
// agg = -dinv[dst] * sum_e dinv[src_e] * w_e * z[src_e]
// MODE 0: z = h (flag dtype, stride 64)   -> Tx1 = agg, bf16 stride-128
// MODE 1: z = Tx1 (bf16 stride-128 rows)  -> Tx2 = 2*agg - h, bf16 stride-128
template<int MODE>
__global__ __launch_bounds__(256)
void k_gath(const int* __restrict__ rowptr, const float* __restrict__ dinv,
            const int2* __restrict__ csr, const void* __restrict__ zin,
            const void* __restrict__ hin, ushort* __restrict__ outv,
            const int* __restrict__ flagp) {
    const int f32 = flagp[0];
    int n = (blockIdx.x * 256 + threadIdx.x) >> 6;   // dst node
    int lane = threadIdx.x & 63;
    if (n >= NN) return;
    int b0 = rowptr[n], e0 = rowptr[n + 1];
    const int2* row = csr + b0;
    int cnt = e0 - b0;
    float acc = 0.f;
    int i = 0;
#define ZLD(sidx) (MODE == 0 ? ldin(zin, (sidx) * 64 + lane, f32) \
                             : b2f_raw(((const ushort*)zin)[(size_t)(sidx) * 128 + lane]))
    for (; i + 3 < cnt; i += 4) {
        int2 p0 = row[i], p1 = row[i + 1], p2 = row[i + 2], p3 = row[i + 3];
        float z0 = ZLD(p0.x), z1 = ZLD(p1.x), z2 = ZLD(p2.x), z3 = ZLD(p3.x);
        acc = fmaf(dinv[p0.x] * __int_as_float(p0.y), z0, acc);
        acc = fmaf(dinv[p1.x] * __int_as_float(p1.y), z1, acc);
        acc = fmaf(dinv[p2.x] * __int_as_float(p2.y), z2, acc);
        acc = fmaf(dinv[p3.x] * __int_as_float(p3.y), z3, acc);
    }
    for (; i < cnt; i++) {
        int2 p0 = row[i];
        float z0 = ZLD(p0.x);
        acc = fmaf(dinv[p0.x] * __int_as_float(p0.y), z0, acc);
    }
#undef ZLD
    float r = -dinv[n] * acc;
    if (MODE == 0) {
        outv[(size_t)n * 128 + lane] = f2bu(r);
    } else {
        float hv = ldin(hin, n * 64 + lane, f32);        // coalesced
        outv[(size_t)n * 128 + lane] = f2bu(2.f * r - hv);
    }
}

// ---------------- pre-swizzle weights into MFMA fragment order ---------
// Wf: [kc 0..9][t 0..15][lane 0..63][j 0..7] bf16, element =
//     W[r = kc*32 + (lane>>4)*8 + j][o = 16t + (lane&15)] with column perm
//     o = 16t+(l&15): gate g = t&3, cc = (t>>2)*16 + (lane&15)
// WlF: [kc2 0..1][t 0..3][lane][j], Wl[k = kc2*32+(l>>4)*8+j][n = 16t+(l&15)]
// biasP[o]: permuted bias
__global__ void k_wcat(const void* __restrict__ Wx, const void* __restrict__ theta,
                       const void* __restrict__ bg, const void* __restrict__ convb,
                       const void* __restrict__ Wl,
                       ushort* __restrict__ Wf, float* __restrict__ biasP,
                       ushort* __restrict__ WlF, const int* __restrict__ flagp) {
    const int f32 = flagp[0];
    int gid = blockIdx.x * 256 + threadIdx.x;   // 336 blocks * 256 = 86016
    if (gid < 81920) {
        int j = gid & 7, l = (gid >> 3) & 63, tile = gid >> 9;
        int kc = tile >> 4, t = tile & 15;
        int r = kc * 32 + ((l >> 4) * 8) + j;
        int g = t & 3;
        int cc = (t >> 2) * 16 + (l & 15);
        float v;
        if (r < 128) {
            v = ldin(Wx, (g * 128 + r) * 64 + cc, f32);
        } else {
            int k3 = (r - 128) >> 6, rr = (r - 128) & 63;
            v = ldin(theta, ((g * 3 + k3) * 64 + rr) * 64 + cc, f32);
        }
        Wf[gid] = f2bu(v);
        if (gid < 256) {
            int o = gid;
            int gg = (o >> 4) & 3;
            int cc2 = (o >> 6) * 16 + (o & 15);
            biasP[o] = ldin(bg, gg * 64 + cc2, f32) + ldin(convb, gg * 64 + cc2, f32);
        }
    } else {
        int gid2 = gid - 81920;                  // [0, 4096)
        int j = gid2 & 7, l = (gid2 >> 3) & 63, tile2 = gid2 >> 9;
        int kc2 = tile2 >> 2, t = tile2 & 3;
        int k = kc2 * 32 + ((l >> 4) * 8) + j;
        int n = t * 16 + (l & 15);
        WlF[gid2] = f2bu(ldin(Wl, k * 64 + n, f32));
    }
}

// ---------------- MFMA gate GEMM [64 nodes x 256 cols] + LSTM + out ----
// F rows: 0-127 x | 128-191 h | 192-255 Tx1 | 256-319 Tx2
// Staging is software-pipelined (prefetch kc+1 before barrier of kc) with
// a double-buffered As -> ONE barrier per chunk.
// Aliasing: Tx1 (bf16, 256B/node footprint) lives in the `out` fp32 region,
// Tx2 in the `c0` region, both with per-node byte ranges inside the node's
// own output slab. Blocks only touch their own 64-node slab; all kc-loop
// reads precede epilogue writes. Safe.
__global__ __launch_bounds__(256)
void k_gates(const void* __restrict__ x, const void* __restrict__ h,
             const void* __restrict__ cin,
             const ushort* __restrict__ Tx1, const ushort* __restrict__ Tx2,
             const ushort* __restrict__ Wf, const float* __restrict__ biasP,
             const ushort* __restrict__ WlF, const void* __restrict__ bl,
             float* __restrict__ outF, float* __restrict__ h0o,
             float* __restrict__ c0o, const int* __restrict__ flagp) {
    const int f32 = flagp[0];
    __shared__ ushort As[2][4 * 64 * 8]; // 8 KB, double-buffered A fragments
    __shared__ ushort Hs[64 * 72];       // 9.2 KB, relu(h0) bf16, padded stride 72
    const int tid = threadIdx.x;
    const int lane = tid & 63;
    const int w = tid >> 6;              // wave 0..3
    const int base = blockIdx.x * 64;
    // staging role: thread -> (node sm, k-quad skq)
    const int sm = tid & 63;
    const int skq = tid >> 6;
    const int snode = base + sm;
    const bool svalid = snode < NN;
    const int soff = (((sm >> 4) * 64) + ((sm & 15) + 16 * skq)) * 8;

    floatx4 acc[4][4];                   // [m-tile][gate]
    {
        float bv0 = biasP[w * 64 + 0 * 16 + (lane & 15)];
        float bv1 = biasP[w * 64 + 1 * 16 + (lane & 15)];
        float bv2 = biasP[w * 64 + 2 * 16 + (lane & 15)];
        float bv3 = biasP[w * 64 + 3 * 16 + (lane & 15)];
#pragma unroll
        for (int mt = 0; mt < 4; mt++) {
            acc[mt][0] = (floatx4){bv0, bv0, bv0, bv0};
            acc[mt][1] = (floatx4){bv1, bv1, bv1, bv1};
            acc[mt][2] = (floatx4){bv2, bv2, bv2, bv2};
            acc[mt][3] = (floatx4){bv3, bv3, bv3, bv3};
        }
    }

    // per-chunk staging load (8 bf16 F-row values for this thread)
    auto produce = [&](int kc) -> uint4 {
        uint4 r = {0, 0, 0, 0};
        if (!svalid) return r;
        if (kc < 4)      r = ld8_bf16(x, snode * 128 + kc * 32 + skq * 8, f32);
        else if (kc < 6) r = ld8_bf16(h, snode * 64 + (kc - 4) * 32 + skq * 8, f32);
        else if (kc < 8) r = *(const uint4*)&Tx1[(size_t)snode * 128 + (kc - 6) * 32 + skq * 8];
        else             r = *(const uint4*)&Tx2[(size_t)snode * 128 + (kc - 8) * 32 + skq * 8];
        return r;
    };

    uint4 raw = produce(0);
    for (int kc = 0; kc < 10; kc++) {
        *(uint4*)&As[kc & 1][soff] = raw;
        if (kc < 9) raw = produce(kc + 1);     // prefetch: hides HBM latency
        // B fragments for this chunk (global, L2-resident)
        short8 bF[4];
#pragma unroll
        for (int g = 0; g < 4; g++)
            bF[g] = *(const short8*)&Wf[((kc * 16 + w * 4 + g) * 64 + lane) * 8];

        __syncthreads();                 // staging of buf kc&1 visible

        short8 aF[4];
#pragma unroll
        for (int mt = 0; mt < 4; mt++)
            aF[mt] = *(const short8*)&As[kc & 1][(mt * 64 + lane) * 8];
#pragma unroll
        for (int mt = 0; mt < 4; mt++)
#pragma unroll
            for (int g = 0; g < 4; g++)
                acc[mt][g] = __builtin_amdgcn_mfma_f32_16x16x32_bf16(
                    aF[mt], bF[g], acc[mt][g], 0, 0, 0);
    }

    // ---- LSTM epilogue, fully in-register (perm put all 4 gates here) ----
    const int cc = w * 16 + (lane & 15);
#pragma unroll
    for (int mt = 0; mt < 4; mt++) {
        const int m0 = mt * 16 + ((lane >> 4) * 4);
#pragma unroll
        for (int r = 0; r < 4; r++) {
            int ml = m0 + r;
            int node = base + ml;
            float gi = sigmoidf(acc[mt][0][r]);
            float gf = sigmoidf(acc[mt][1][r]);
            float gt = tanh_fast(acc[mt][2][r]);
            float go = sigmoidf(acc[mt][3][r]);
            float cv = (node < NN) ? ldin(cin, node * 64 + cc, f32) : 0.f;
            float c0 = gf * cv + gi * gt;
            float h0v = go * tanh_fast(c0);
            if (node < NN) {
                c0o[node * 64 + cc] = c0;
                h0o[node * 64 + cc] = h0v;
            }
            Hs[ml * 72 + cc] = f2bu(fmaxf(h0v, 0.f));
        }
    }
    __syncthreads();

    // ---- fused out = relu(h0) @ Wl + bl (8 MFMA per wave) ----
    float blv = ldin(bl, w * 16 + (lane & 15), f32);
    floatx4 oacc[4];
#pragma unroll
    for (int mt = 0; mt < 4; mt++) oacc[mt] = (floatx4){blv, blv, blv, blv};
#pragma unroll
    for (int kc2 = 0; kc2 < 2; kc2++) {
        short8 bW = *(const short8*)&WlF[((kc2 * 4 + w) * 64 + lane) * 8];
#pragma unroll
        for (int mt = 0; mt < 4; mt++) {
            short8 aH = *(const short8*)&Hs[(mt * 16 + (lane & 15)) * 72
                                            + kc2 * 32 + (lane >> 4) * 8];
            oacc[mt] = __builtin_amdgcn_mfma_f32_16x16x32_bf16(
                aH, bW, oacc[mt], 0, 0, 0);
        }
    }
#pragma unroll
    for (int mt = 0; mt < 4; mt++) {
        const int m0 = mt * 16 + ((lane >> 4) * 4);
#pragma unroll
        for (int r = 0; r < 4; r++) {
            int node = base + m0 + r;
            if (node < NN)
                outF[node * 64 + w * 16 + (lane & 15)] = oacc[mt][r];
        }
    }
}

extern "C" void kernel_launch(void* const* d_in, const int* in_sizes, int n_in,
                              void* d_out, int out_size, void* d_ws, size_t ws_size,
                              hipStream_t stream) {
    const void* x     = d_in[0];
    const int*  ei    = (const int*)d_in[1];
    const void* ew    = d_in[2];
    const void* h     = d_in[3];
    const void* c     = d_in[4];
    const void* Wx    = d_in[5];
    const void* bg    = d_in[6];
    const void* theta = d_in[7];
    const void* convb = d_in[8];
    const void* Wl    = d_in[9];
    const void* bl    = d_in[10];
    (void)in_sizes; (void)n_in; (void)out_size; (void)ws_size;

    // ws layout (4B words) — ~1.78 MB total
    float*  ws     = (float*)d_ws;
    int*    flag   = (int*)ws;                 // 64
    float*  dinv   = ws + 64;                  // 100000
    int*    rowptr = (int*)(ws + 100064);      // 100001 (pad to 100064)
    int*    gcntD  = (int*)(ws + 200128);      // 256
    int*    gcntS  = (int*)(ws + 200384);      // 256
    int*    bbaseD = (int*)(ws + 200640);      // 197 (pad 256)
    int*    bbaseS = (int*)(ws + 200896);      // 197
    int*    gcurD  = (int*)(ws + 201152);      // 256
    int*    gcurS  = (int*)(ws + 201408);      // 256
    float*  biasP  = ws + 400128;              // 256
    ushort* Wf     = (ushort*)(ws + 400384);   // 81920 ushort = 40960 words
    ushort* WlF    = (ushort*)(ws + 441344);   // 4096 ushort = 2048 words

    // d_out FP32: out [0,6.4M) | h0 [6.4M,12.8M) | c0 [12.8M,19.2M)  (words)
    float* outF = (float*)d_out;
    float* h0o  = outF + (size_t)NN * 64;
    float* c0o  = outF + (size_t)2 * NN * 64;
    // Tx1 bf16 aliases the out region; Tx2 bf16 aliases the c0 region —
    // node n occupies ushort [n*128, n*128+64) = bytes [n*256, n*256+128),
    // inside node n's own output slab.
    ushort* Tx1b = (ushort*)outF;
    ushort* Tx2b = (ushort*)c0o;
    // h0 region (6.4M words): recD [0,3.2M) + csr [3.2M,6.4M)
    //   recD written by k_part, read by k_build; csr written by k_build,
    //   read by gaths; whole region overwritten by k_gates h0 at the end.
    int2* recD = (int2*)h0o;
    int2* csr  = (int2*)(h0o + 3200000);
    // c0 region: recS [0,3.2M) — dead after k_build, then Tx2 overwrites.
    int2* recS = (int2*)c0o;

    k_sniff<<<1, 256, 0, stream>>>(x, flag);
    hipMemsetAsync(gcntD, 0, 512 * 4, stream);   // gcntD + gcntS

    k_count<<<(NE + 4095) / 4096, 256, 0, stream>>>(ei, gcntD, gcntS);
    k_scanb<<<1, 256, 0, stream>>>(gcntD, gcntS, bbaseD, bbaseS, gcurD, gcurS, rowptr);
    k_part<<<(NE + 2047) / 2048, 256, 0, stream>>>(ei, ew, gcurD, gcurS,
                                                   recD, recS, flag);
    k_build<<<NBUCK, 512, 0, stream>>>(recD, recS, bbaseD, bbaseS,
                                       rowptr, csr, dinv);
    k_wcat<<<336, 256, 0, stream>>>(Wx, theta, bg, convb, Wl, Wf, biasP, WlF, flag);

    k_gath<0><<<25000, 256, 0, stream>>>(rowptr, dinv, csr, h,    h, Tx1b, flag);
    k_gath<1><<<25000, 256, 0, stream>>>(rowptr, dinv, csr, Tx1b, h, Tx2b, flag);

    k_gates<<<(NN + 63) / 64, 256, 0, stream>>>(x, h, c, Tx1b, Tx2b,
                                                Wf, biasP, WlF, bl,
                                                outF, h0o, c0o, flag);
}